// Round 6
// baseline (364.496 us; speedup 1.0000x reference)
//
#include <hip/hip_runtime.h>
#include <hip/hip_bf16.h>

typedef __attribute__((ext_vector_type(8))) short short8;
typedef __attribute__((ext_vector_type(4))) float f32x4;

// ---------------- constants ----------------
namespace {
constexpr int Bn  = 64;
constexpr int Cn  = 64;
constexpr int C1O = 32, C2O = 64;
constexpr int L1O = 249, L1P = 124;
constexpr int L2O = 55,  L2P = 27;
constexpr int LIN1K = C2O * L2P;      // 1728

// stats floats (zeroed region: idx < 8384)
constexpr long S2S = 0;          // 4096 conv2 sum
constexpr long S2Q = 4096;       // 4096 conv2 sumsq
constexpr long G1S = 8192;       // 64 gbn1 sum
constexpr long G1Q = 8256;       // 64 gbn1 sumsq
constexpr long G2S = 8320;       // 32 gbn2 sum
constexpr long G2Q = 8352;       // 32 gbn2 sumsq
constexpr long P1P = 8448;       // conv1 partials [2048 co][8 bg][2] = 32768 f (no init needed)

// byte offsets
constexpr long LR0_B  = 165888;      // 4096 f   -> 182272
constexpr long LR1_B  = 182272;      // 1024 f   -> 186368
constexpr long W1RB_B = 186368;      // 163840 bf16 -> 514048
constexpr long W2RB_B = 514048;      // 40960 bf16  -> 595968
constexpr long W2B_B  = 595968;      // 2097152 bf16 -> 4790272
constexpr long P1B_B  = 4790272;     // 16252928 bf16 -> 37296128
constexpr long Y2_B   = 37296128;    // 14417920 bf16 -> 66131968
constexpr long QB_B   = 94867456;    // 7077888 bf16 -> 109023232
constexpr long CO_B   = 109023232;   // 2097152 f -> 117411840
constexpr long XK_B   = 4790272;     // alias p1b/y2 (dead): 5*2097152 bf16 -> 25761792
constexpr long CH1_B  = 117411840;   // 262144 f -> 118460416
constexpr long CH2_B  = 118460416;   // 262144 f -> 119508992
constexpr long FO1_B  = 119508992;   // 32768 f
}

__device__ __forceinline__ unsigned short f2bf(float f) {
    union { float f; unsigned u; } v; v.f = f;
    unsigned r = v.u + 0x7FFFu + ((v.u >> 16) & 1u);
    return (unsigned short)(r >> 16);
}
__device__ __forceinline__ float bf2f(unsigned short s) {
    union { unsigned u; float f; } v; v.u = ((unsigned)s) << 16;
    return v.f;
}
__device__ __forceinline__ short8 cvt8(float4 a, float4 b) {
    float f[8] = {a.x, a.y, a.z, a.w, b.x, b.y, b.z, b.w};
    union { unsigned short s[8]; short8 v; } r;
#pragma unroll
    for (int i = 0; i < 8; ++i) r.s[i] = f2bf(f[i]);
    return r.v;
}
__device__ __forceinline__ uint2 pack4(float4 a) {
    union { unsigned short s[4]; uint2 u; } r;
    r.s[0] = f2bf(a.x); r.s[1] = f2bf(a.y); r.s[2] = f2bf(a.z); r.s[3] = f2bf(a.w);
    return r.u;
}

// ---------------- K1: fused prep + conv1 pass1 (partial stats, no atomics) ----------------
__global__ __launch_bounds__(256) void k1_prep_conv1_kernel(
    const float* __restrict__ inp, const float* __restrict__ w1, const float* __restrict__ b1,
    const float* __restrict__ L0, const float* __restrict__ L1m,
    const int* __restrict__ lmax0, const int* __restrict__ lmax1,
    const float* __restrict__ cl1w, const float* __restrict__ cl2w,
    const float* __restrict__ conv2w, float* __restrict__ ws)
{
    int bid = blockIdx.x;
    int tid = threadIdx.x;
    if (bid < 512) {
        // ---- conv1 pass1: block = (c, 8-batch group) ----
        int c = bid >> 3, bg = bid & 7;
        __shared__ float xs[8][512];
        __shared__ float rs[8][32], rq[8][32];
#pragma unroll
        for (int it = 0; it < 4; ++it) {
            int f4 = it * 256 + tid;
            int bl = f4 >> 7, off = (f4 & 127) * 4;
            *(float4*)&xs[bl][off] = *(const float4*)&inp[((long)(bg * 8 + bl) * 64 + c) * 512 + off];
        }
        int o = tid & 31, bq = tid >> 5;
        int co = c * 32 + o;
        float w[16];
#pragma unroll
        for (int t = 0; t < 16; ++t) w[t] = w1[co * 16 + t];
        float bias = b1[co];
        __syncthreads();
        float s = 0.f, q = 0.f;
        for (int jg = 0; jg < 31; ++jg) {
            float x[32];
#pragma unroll
            for (int h = 0; h < 8; ++h) *(float4*)&x[h * 4] = *(const float4*)&xs[bq][jg * 16 + h * 4];
#pragma unroll
            for (int j = 0; j < 8; ++j) {
                float a = bias;
#pragma unroll
                for (int t = 0; t < 16; ++t) a = fmaf(x[2 * j + t], w[t], a);
                a = fmaxf(a, 0.f);
                s += a; q += a * a;
            }
        }
        {   // l = 248
            float x[16];
#pragma unroll
            for (int h = 0; h < 4; ++h) *(float4*)&x[h * 4] = *(const float4*)&xs[bq][496 + h * 4];
            float a = bias;
#pragma unroll
            for (int t = 0; t < 16; ++t) a = fmaf(x[t], w[t], a);
            a = fmaxf(a, 0.f);
            s += a; q += a * a;
        }
        rs[bq][o] = s; rq[bq][o] = q;
        __syncthreads();
        if (tid < 32) {
            float ss = 0.f, qq = 0.f;
#pragma unroll
            for (int i = 0; i < 8; ++i) { ss += rs[i][tid]; qq += rq[i][tid]; }
            ws[P1P + (long)(c * 32 + tid) * 16 + bg * 2]     = ss;
            ws[P1P + (long)(c * 32 + tid) * 16 + bg * 2 + 1] = qq;
        }
    } else {
        // ---- prep ----
        long idx = (long)(bid - 512) * 256 + tid;
        float inv0 = 2.0f / (float)lmax0[0];
        float inv1 = 2.0f / (float)lmax1[0];
        char* wsb = (char*)ws;
        float* LR0p = (float*)(wsb + LR0_B);
        float* LR1p = (float*)(wsb + LR1_B);
        unsigned short* W1Rp = (unsigned short*)(wsb + W1RB_B);
        unsigned short* W2Rp = (unsigned short*)(wsb + W2RB_B);
        unsigned short* w2b  = (unsigned short*)(wsb + W2B_B);
        if (idx < 8384) {
            ws[idx] = 0.f;
        } else if (idx < 8384 + 4096) {
            long t = idx - 8384; int i = t / 64, j = t % 64;
            LR0p[t] = L0[t] * inv0 - (i == j ? 1.0f : 0.0f);
        } else if (idx < 8384 + 4096 + 1024) {
            long t = idx - 8384 - 4096; int i = t / 32, j = t % 32;
            LR1p[t] = L1m[t] * inv1 - (i == j ? 1.0f : 0.0f);
        } else if (idx < 8384 + 4096 + 1024 + 163840) {
            long t = idx - 8384 - 4096 - 1024;
            int k = t / 32768; int r = t % 32768; int o = r / 512, f = r % 512;
            W1Rp[t] = f2bf(cl1w[o * 2560 + f * 5 + k]);
        } else if (idx < 8384 + 4096 + 1024 + 163840 + 40960) {
            long t = idx - 8384 - 4096 - 1024 - 163840;
            int k = t / 8192; int r = t % 8192; int o = r / 64, f = r % 64;
            W2Rp[t] = f2bf(cl2w[o * 320 + f * 5 + k]);
        } else if (idx < 8384 + 4096 + 1024 + 163840 + 40960 + 2097152) {
            long t = idx - 8384 - 4096 - 1024 - 163840 - 40960;
            w2b[t] = f2bf(conv2w[t]);
        }
    }
}

// ---------------- conv1 pass2: conv+bn+pool -> p1b bf16 [c][b][o][124] ----------------
__global__ __launch_bounds__(256) void conv1_p2_kernel(const float* __restrict__ inp,
    const float* __restrict__ w1, const float* __restrict__ b1,
    const float* __restrict__ g, const float* __restrict__ be,
    const float* __restrict__ ws, unsigned short* __restrict__ p1)
{
    int c = blockIdx.x >> 3, bg = blockIdx.x & 7;
    __shared__ float xs[8][512];
    int tid = threadIdx.x;
#pragma unroll
    for (int it = 0; it < 4; ++it) {
        int f4 = it * 256 + tid;
        int bl = f4 >> 7, off = (f4 & 127) * 4;
        *(float4*)&xs[bl][off] = *(const float4*)&inp[((long)(bg * 8 + bl) * 64 + c) * 512 + off];
    }
    int o = tid & 31, bq = tid >> 5;
    int co = c * 32 + o;
    float w[16];
#pragma unroll
    for (int t = 0; t < 16; ++t) w[t] = w1[co * 16 + t];
    float bias = b1[co];
    float ssum = 0.f, qsum = 0.f;
#pragma unroll
    for (int i = 0; i < 8; ++i) {
        ssum += ws[P1P + (long)co * 16 + i * 2];
        qsum += ws[P1P + (long)co * 16 + i * 2 + 1];
    }
    float N = (float)(Bn * L1O);
    float m = ssum / N;
    float inv = rsqrtf(qsum / N - m * m + 1e-5f);
    float sc = inv * g[co], sh = be[co] - m * sc;
    __syncthreads();
    unsigned short* op = p1 + ((long)(c * 64 + bg * 8 + bq) * 32 + o) * 124;
    for (int jg = 0; jg < 31; ++jg) {
        float x[32];
#pragma unroll
        for (int h = 0; h < 8; ++h) *(float4*)&x[h * 4] = *(const float4*)&xs[bq][jg * 16 + h * 4];
        union { unsigned short r[4]; uint2 u; } pk;
#pragma unroll
        for (int p = 0; p < 4; ++p) {
            float a0 = bias, a1 = bias;
#pragma unroll
            for (int t = 0; t < 16; ++t) {
                a0 = fmaf(x[4 * p + t], w[t], a0);
                a1 = fmaf(x[4 * p + 2 + t], w[t], a1);
            }
            float v0 = fmaxf(a0, 0.f) * sc + sh;
            float v1 = fmaxf(a1, 0.f) * sc + sh;
            pk.r[p] = f2bf(fmaxf(v0, v1));
        }
        *(uint2*)&op[jg * 4] = pk.u;
    }
}

// ---------------- conv2 MFMA GEMM, M-tile 256 + relu + stats; y2 bf16 [c][b][l][o2] ----------------
__global__ __launch_bounds__(256) void conv2_mfma_kernel(const unsigned short* __restrict__ p1b,
    const unsigned short* __restrict__ w2b, const float* __restrict__ b2,
    unsigned short* __restrict__ y2b, float* __restrict__ s2s, float* __restrict__ s2q)
{
    int c = blockIdx.y;
    int m0 = blockIdx.x * 256;
    __shared__ unsigned short Bl[64 * 512];
    __shared__ float red[2][4][64];
    int tid = threadIdx.x;
    int w = tid >> 6, lane = tid & 63;
    int lx = lane & 15, g = lane >> 4;

    const unsigned short* wsrc = w2b + (long)c * 32768;
#pragma unroll
    for (int it = 0; it < 16; ++it) {
        int j = it * 256 + tid;
        int n = j >> 6, kb = j & 63;
        uint4 val = *(const uint4*)(wsrc + n * 512 + kb * 8);
        int dst = (n * 1024 + kb * 16) ^ ((n & 7) << 4);
        *(uint4*)((char*)Bl + dst) = val;
    }
    __syncthreads();

    const unsigned short* abase[4];
#pragma unroll
    for (int ma = 0; ma < 4; ++ma) {
        int m = m0 + w * 64 + ma * 16 + lx;
        m = min(m, 3519);
        int b = m / 55, lp = m % 55;
        abase[ma] = p1b + ((long)(c * 64 + b) * 32) * 124 + 2 * lp + (g & 1) * 8;
    }
    int cio = g >> 1;

    f32x4 acc[4][4] = {};
    for (int kstep = 0; kstep < 16; ++kstep) {
        short8 af[4];
#pragma unroll
        for (int ma = 0; ma < 4; ++ma) {
            const unsigned short* ap = abase[ma] + (kstep * 2 + cio) * 124;
            union { unsigned u[4]; short8 v; } t;
            t.u[0] = *(const unsigned*)(ap + 0);
            t.u[1] = *(const unsigned*)(ap + 2);
            t.u[2] = *(const unsigned*)(ap + 4);
            t.u[3] = *(const unsigned*)(ap + 6);
            af[ma] = t.v;
        }
#pragma unroll
        for (int fi = 0; fi < 4; ++fi) {
            int n = fi * 16 + lx;
            int off = (n * 1024 + kstep * 64 + g * 16) ^ ((n & 7) << 4);
            short8 bfrag = *(const short8*)((char*)Bl + off);
#pragma unroll
            for (int ma = 0; ma < 4; ++ma)
                acc[ma][fi] = __builtin_amdgcn_mfma_f32_16x16x32_bf16(af[ma], bfrag, acc[ma][fi], 0, 0, 0);
        }
    }

    float cs[4] = {}, cq[4] = {};
#pragma unroll
    for (int fi = 0; fi < 4; ++fi) {
        int o2 = fi * 16 + lx;
        float bia = b2[c * 64 + o2];
#pragma unroll
        for (int ma = 0; ma < 4; ++ma) {
#pragma unroll
            for (int r = 0; r < 4; ++r) {
                int mm = m0 + w * 64 + ma * 16 + g * 4 + r;
                if (mm < 3520) {
                    int bb = mm / 55, ll = mm % 55;
                    float y = fmaxf(acc[ma][fi][r] + bia, 0.f);
                    y2b[((long)(c * 64 + bb) * 55 + ll) * 64 + o2] = f2bf(y);
                    cs[fi] += y; cq[fi] += y * y;
                }
            }
        }
    }
#pragma unroll
    for (int fi = 0; fi < 4; ++fi) {
        cs[fi] += __shfl_xor(cs[fi], 16); cs[fi] += __shfl_xor(cs[fi], 32);
        cq[fi] += __shfl_xor(cq[fi], 16); cq[fi] += __shfl_xor(cq[fi], 32);
    }
    __syncthreads();
    if (g == 0) {
#pragma unroll
        for (int fi = 0; fi < 4; ++fi) { red[0][w][fi * 16 + lx] = cs[fi]; red[1][w][fi * 16 + lx] = cq[fi]; }
    }
    __syncthreads();
    if (tid < 64) {
        float ss = red[0][0][tid] + red[0][1][tid] + red[0][2][tid] + red[0][3][tid];
        float qq = red[1][0][tid] + red[1][1][tid] + red[1][2][tid] + red[1][3][tid];
        atomicAdd(&s2s[c * 64 + tid], ss);
        atomicAdd(&s2q[c * 64 + tid], qq);
    }
}

// ---------------- conv2 bn + pool via LDS transpose; block per (c,b) ----------------
__global__ __launch_bounds__(256) void bn2_pool_kernel(const unsigned short* __restrict__ y2b,
    const float* __restrict__ ws, const float* __restrict__ g, const float* __restrict__ be,
    unsigned short* __restrict__ q)
{
    int bid = blockIdx.x;              // c*64+b
    int c = bid >> 6;
    __shared__ unsigned short t2[55][66];
    const unsigned* src = (const unsigned*)(y2b + (long)bid * 3520);
    for (int i = threadIdx.x; i < 1760; i += 256) {
        int r = i >> 5, cu = i & 31;
        *(unsigned*)&t2[r][cu * 2] = src[i];
    }
    __syncthreads();
    float N = (float)(Bn * L2O);
    unsigned short* qp = q + (long)bid * 1728;
    for (int t = threadIdx.x; t < 1728; t += 256) {
        int o2 = t / 27, j = t - o2 * 27;
        int co = c * 64 + o2;
        float m = ws[S2S + co] / N;
        float inv = rsqrtf(ws[S2Q + co] / N - m * m + 1e-5f);
        float sc = inv * g[co], sh = be[co] - m * sc;
        float v = fmaxf(sc * bf2f(t2[2 * j][o2]) + sh, sc * bf2f(t2[2 * j + 1][o2]) + sh);
        qp[t] = f2bf(v);
    }
}

// ---------------- generic MFMA GEMM (lin1): C[64,Ntot] = relu(A_bf16[64,K] @ W_fp32[Ntot,K]^T + b) ----
__global__ __launch_bounds__(256) void gemm_a16w32_kernel(const unsigned short* __restrict__ A,
    const float* __restrict__ W, const float* __restrict__ bias, float* __restrict__ C,
    int K, int Ntot, long sA, long sW, long sB, long sC)
{
    int c = blockIdx.y;
    A += (long)c * sA; W += (long)c * sW; bias += (long)c * sB; C += (long)c * sC;
    int n0 = blockIdx.x * 64;
    int tid = threadIdx.x, wv = tid >> 6, lane = tid & 63;
    int lx = lane & 15, g = lane >> 4;
    int wm = wv & 1, wn = wv >> 1;

    const unsigned short* a0 = A + (long)(wm * 32 + lx) * K + g * 8;
    const float* w0 = W + (long)(n0 + wn * 32 + lx) * K + g * 8;
    int ksteps = K >> 5;

    f32x4 acc[2][2] = {};
    for (int kstep = 0; kstep < ksteps; ++kstep) {
        short8 af[2];
        af[0] = *(const short8*)(a0 + kstep * 32);
        af[1] = *(const short8*)(a0 + (long)16 * K + kstep * 32);
        short8 bf[2];
#pragma unroll
        for (int nb = 0; nb < 2; ++nb) {
            const float* wp = w0 + (long)nb * 16 * K + kstep * 32;
            float4 x = *(const float4*)(wp);
            float4 y = *(const float4*)(wp + 4);
            bf[nb] = cvt8(x, y);
        }
#pragma unroll
        for (int ma = 0; ma < 2; ++ma)
#pragma unroll
            for (int nb = 0; nb < 2; ++nb)
                acc[ma][nb] = __builtin_amdgcn_mfma_f32_16x16x32_bf16(af[ma], bf[nb], acc[ma][nb], 0, 0, 0);
    }
#pragma unroll
    for (int ma = 0; ma < 2; ++ma)
#pragma unroll
        for (int nb = 0; nb < 2; ++nb) {
            int o = n0 + wn * 32 + nb * 16 + lx;
            float bia = bias[o];
#pragma unroll
            for (int r = 0; r < 4; ++r) {
                int b = wm * 32 + ma * 16 + g * 4 + r;
                C[(long)b * Ntot + o] = fmaxf(acc[ma][nb][r] + bia, 0.f);
            }
        }
}

// ---------------- fused chebyshev recursion V=64: x0..x4, bf16 stores ----------------
__global__ __launch_bounds__(256) void rec_fused_kernel(const float* __restrict__ Lr,
    const float* __restrict__ co, const int* __restrict__ perm, unsigned short* __restrict__ xkb)
{
    __shared__ float Lt[64 * 64];     // Lt[u][v] = Lr[v][u]
    __shared__ float xA[64][130];
    __shared__ float xB[64][130];
    int tid = threadIdx.x;
    for (int i = tid; i < 4096; i += 256) Lt[(i & 63) * 64 + (i >> 6)] = Lr[i];
    int cg = tid & 31, vg = tid >> 5;
    int col = blockIdx.x * 128 + cg * 4;
#pragma unroll
    for (int i = 0; i < 8; ++i) {
        int v = vg * 8 + i;
        float4 x = *(const float4*)&co[(long)perm[v] * 32768 + col];
        *(float4*)&xA[v][cg * 4] = x;
        *(uint2*)&xkb[(long)v * 32768 + col] = pack4(x);
    }
    __syncthreads();
#pragma unroll
    for (int k = 1; k <= 4; ++k) {
        float (*prev)[130] = (k & 1) ? xA : xB;
        float (*dst)[130]  = (k & 1) ? xB : xA;
        float acc[8][4] = {};
        for (int u = 0; u < 64; ++u) {
            float4 xv = *(const float4*)&prev[u][cg * 4];
            float4 l0 = *(const float4*)&Lt[u * 64 + vg * 8];
            float4 l1 = *(const float4*)&Lt[u * 64 + vg * 8 + 4];
            float lv[8] = {l0.x, l0.y, l0.z, l0.w, l1.x, l1.y, l1.z, l1.w};
#pragma unroll
            for (int i = 0; i < 8; ++i) {
                acc[i][0] = fmaf(lv[i], xv.x, acc[i][0]);
                acc[i][1] = fmaf(lv[i], xv.y, acc[i][1]);
                acc[i][2] = fmaf(lv[i], xv.z, acc[i][2]);
                acc[i][3] = fmaf(lv[i], xv.w, acc[i][3]);
            }
        }
#pragma unroll
        for (int i = 0; i < 8; ++i) {
            int v = vg * 8 + i;
            float4 r;
            if (k == 1) {
                r.x = acc[i][0]; r.y = acc[i][1]; r.z = acc[i][2]; r.w = acc[i][3];
            } else {
                float4 p = *(const float4*)&dst[v][cg * 4];   // holds x_{k-2}
                r.x = 2.f * acc[i][0] - p.x; r.y = 2.f * acc[i][1] - p.y;
                r.z = 2.f * acc[i][2] - p.z; r.w = 2.f * acc[i][3] - p.w;
            }
            *(float4*)&dst[v][cg * 4] = r;
            *(uint2*)&xkb[(long)k * 2097152 + (long)v * 32768 + col] = pack4(r);
        }
        __syncthreads();
    }
}

// ---------------- cheby layer-1 output GEMM + gbn1 stats atomics ----------------
__global__ __launch_bounds__(256) void cheby1_mfma_kernel(const unsigned short* __restrict__ xkb,
    const unsigned short* __restrict__ w1rb, const float* __restrict__ bias,
    float* __restrict__ out, float* __restrict__ g1s, float* __restrict__ g1q)
{
    int m0 = blockIdx.x * 16;
    __shared__ unsigned short Bl[64 * 512];
    __shared__ float rS[4][16], rQ[4][16];
    int tid = threadIdx.x, wv = tid >> 6, lane = tid & 63;
    int lx = lane & 15, g = lane >> 4;
    int m = m0 + lx;
    int v = m & 63, b = m >> 6;

    f32x4 acc = {};
    for (int kc = 0; kc < 5; ++kc) {
        __syncthreads();
#pragma unroll
        for (int it = 0; it < 16; ++it) {
            int j = it * 256 + tid;
            int n = j >> 6, kb = j & 63;
            uint4 val = *(const uint4*)(w1rb + (long)kc * 32768 + n * 512 + kb * 8);
            int dst = (n * 1024 + kb * 16) ^ ((n & 7) << 4);
            *(uint4*)((char*)Bl + dst) = val;
        }
        __syncthreads();
        const unsigned short* ab = xkb + (long)(kc * 64 + v) * 32768 + b * 512 + g * 8;
        for (int kl = 0; kl < 16; ++kl) {
            short8 af = *(const short8*)(ab + kl * 32);
            int n = wv * 16 + lx;
            int off = (n * 1024 + kl * 64 + g * 16) ^ ((n & 7) << 4);
            short8 bfrag = *(const short8*)((char*)Bl + off);
            acc = __builtin_amdgcn_mfma_f32_16x16x32_bf16(af, bfrag, acc, 0, 0, 0);
        }
    }
    int o = wv * 16 + lx;
    float bia = bias[o];
    float sv[4], qv[4];
#pragma unroll
    for (int r = 0; r < 4; ++r) {
        int mm = m0 + g * 4 + r;
        int vv = mm & 63, bb = mm >> 6;
        float val = fmaxf(acc[r] + bia, 0.f);
        out[((long)(bb * 64 + vv)) * 64 + o] = val;
        sv[r] = val; qv[r] = val * val;
    }
    // gbn1 stats: per-row sums (over o) -> atomics per v
#pragma unroll
    for (int r = 0; r < 4; ++r) {
#pragma unroll
        for (int msk = 1; msk < 16; msk <<= 1) {
            sv[r] += __shfl_xor(sv[r], msk);
            qv[r] += __shfl_xor(qv[r], msk);
        }
    }
    if (lx == 0) {
#pragma unroll
        for (int r = 0; r < 4; ++r) { rS[wv][g * 4 + r] = sv[r]; rQ[wv][g * 4 + r] = qv[r]; }
    }
    __syncthreads();
    if (tid < 16) {
        float ss = rS[0][tid] + rS[1][tid] + rS[2][tid] + rS[3][tid];
        float qq = rQ[0][tid] + rQ[1][tid] + rQ[2][tid] + rQ[3][tid];
        int vv = (m0 + tid) & 63;
        atomicAdd(&g1s[vv], ss);
        atomicAdd(&g1q[vv], qq);
    }
}

// ---------------- fused layer 2: gbn1(norm+pool) on load + cheby rec + MFMA + gbn2 stats ----------------
__global__ __launch_bounds__(256) void layer2_kernel(const float* __restrict__ ch1,
    const float* __restrict__ g1s, const float* __restrict__ g1q,
    const float* __restrict__ gbn1g, const float* __restrict__ gbn1b,
    const float* __restrict__ Lr1, const unsigned short* __restrict__ w2rb,
    const float* __restrict__ bias, float* __restrict__ out,
    float* __restrict__ g2s, float* __restrict__ g2q)
{
    int b = blockIdx.x;
    __shared__ float xs[5][32][72];
    __shared__ unsigned short wsl[128 * 320];
    __shared__ float r2S[4][32], r2Q[4][32];
    int tid = threadIdx.x;
#pragma unroll
    for (int it = 0; it < 20; ++it) {
        int j = it * 256 + tid;
        int o = j / 40, kb = j % 40;
        uint4 val = *(const uint4*)(w2rb + ((long)(kb >> 3) * 128 + o) * 64 + (kb & 7) * 8);
        int dst = (o * 640 + kb * 16) ^ ((o & 7) << 4);
        *(uint4*)((char*)wsl + dst) = val;
    }
    int v = tid & 31, fg = tid >> 5;
    float lrow[32];
#pragma unroll
    for (int u = 0; u < 32; ++u) lrow[u] = Lr1[v * 32 + u];
    {
        // fused gbn1 normalize + gpool: xs[0][v][f] from ch1[b][2v / 2v+1][f]
        float N1 = 4096.f;
        float mA = g1s[2 * v] / N1;
        float iA = rsqrtf(g1q[2 * v] / N1 - mA * mA + 64.0f);
        float mB = g1s[2 * v + 1] / N1;
        float iB = rsqrtf(g1q[2 * v + 1] / N1 - mB * mB + 64.0f);
        float sc0 = iA * gbn1g[2 * v], sh0 = gbn1b[2 * v] - mA * sc0;
        float sc1 = iB * gbn1g[2 * v + 1], sh1 = gbn1b[2 * v + 1] - mB * sc1;
        const float* c0 = ch1 + ((long)b * 64 + 2 * v) * 64 + fg * 8;
        float4 a0 = *(const float4*)c0;
        float4 a1 = *(const float4*)(c0 + 4);
        float4 b0 = *(const float4*)(c0 + 64);
        float4 b1 = *(const float4*)(c0 + 68);
        float4 r0, r1;
        r0.x = fmaxf(sc0 * a0.x + sh0, sc1 * b0.x + sh1);
        r0.y = fmaxf(sc0 * a0.y + sh0, sc1 * b0.y + sh1);
        r0.z = fmaxf(sc0 * a0.z + sh0, sc1 * b0.z + sh1);
        r0.w = fmaxf(sc0 * a0.w + sh0, sc1 * b0.w + sh1);
        r1.x = fmaxf(sc0 * a1.x + sh0, sc1 * b1.x + sh1);
        r1.y = fmaxf(sc0 * a1.y + sh0, sc1 * b1.y + sh1);
        r1.z = fmaxf(sc0 * a1.z + sh0, sc1 * b1.z + sh1);
        r1.w = fmaxf(sc0 * a1.w + sh0, sc1 * b1.w + sh1);
        *(float4*)&xs[0][v][fg * 8] = r0;
        *(float4*)&xs[0][v][fg * 8 + 4] = r1;
    }
    __syncthreads();
    for (int k = 1; k < 5; ++k) {
        float acc[8] = {};
#pragma unroll
        for (int u = 0; u < 32; ++u) {
            float4 xa = *(const float4*)&xs[k - 1][u][fg * 8];
            float4 xb = *(const float4*)&xs[k - 1][u][fg * 8 + 4];
            float l = lrow[u];
            acc[0] = fmaf(l, xa.x, acc[0]); acc[1] = fmaf(l, xa.y, acc[1]);
            acc[2] = fmaf(l, xa.z, acc[2]); acc[3] = fmaf(l, xa.w, acc[3]);
            acc[4] = fmaf(l, xb.x, acc[4]); acc[5] = fmaf(l, xb.y, acc[5]);
            acc[6] = fmaf(l, xb.z, acc[6]); acc[7] = fmaf(l, xb.w, acc[7]);
        }
        float4 ra, rb;
        if (k >= 2) {
            float4 pa = *(const float4*)&xs[k - 2][v][fg * 8];
            float4 pb = *(const float4*)&xs[k - 2][v][fg * 8 + 4];
            ra.x = 2.f * acc[0] - pa.x; ra.y = 2.f * acc[1] - pa.y;
            ra.z = 2.f * acc[2] - pa.z; ra.w = 2.f * acc[3] - pa.w;
            rb.x = 2.f * acc[4] - pb.x; rb.y = 2.f * acc[5] - pb.y;
            rb.z = 2.f * acc[6] - pb.z; rb.w = 2.f * acc[7] - pb.w;
        } else {
            ra.x = acc[0]; ra.y = acc[1]; ra.z = acc[2]; ra.w = acc[3];
            rb.x = acc[4]; rb.y = acc[5]; rb.z = acc[6]; rb.w = acc[7];
        }
        *(float4*)&xs[k][v][fg * 8] = ra;
        *(float4*)&xs[k][v][fg * 8 + 4] = rb;
        __syncthreads();
    }
    int wv = tid >> 6, lane = tid & 63;
    int lx = lane & 15, g = lane >> 4;
    f32x4 acc2[2][2] = {};
    for (int kstep = 0; kstep < 10; ++kstep) {
        int k = kstep * 32 + g * 8;
        int kc = k >> 6, f = k & 63;
        short8 af[2];
#pragma unroll
        for (int ma = 0; ma < 2; ++ma) {
            int vv = ma * 16 + lx;
            float4 xa = *(const float4*)&xs[kc][vv][f];
            float4 xb = *(const float4*)&xs[kc][vv][f + 4];
            af[ma] = cvt8(xa, xb);
        }
#pragma unroll
        for (int nb = 0; nb < 2; ++nb) {
            int o = wv * 32 + nb * 16 + lx;
            int kb = kstep * 4 + g;
            int off = (o * 640 + kb * 16) ^ ((o & 7) << 4);
            short8 bf = *(const short8*)((char*)wsl + off);
#pragma unroll
            for (int ma = 0; ma < 2; ++ma)
                acc2[ma][nb] = __builtin_amdgcn_mfma_f32_16x16x32_bf16(af[ma], bf, acc2[ma][nb], 0, 0, 0);
        }
    }
    float s2[2][4] = {}, q2[2][4] = {};
#pragma unroll
    for (int ma = 0; ma < 2; ++ma)
#pragma unroll
        for (int nb = 0; nb < 2; ++nb) {
            int o = wv * 32 + nb * 16 + lx;
            float bia = bias[o];
#pragma unroll
            for (int r = 0; r < 4; ++r) {
                int vv = ma * 16 + g * 4 + r;
                float val = fmaxf(acc2[ma][nb][r] + bia, 0.f);
                out[((long)b * 32 + vv) * 128 + o] = val;
                s2[ma][r] += val; q2[ma][r] += val * val;
            }
        }
    // gbn2 stats: per-row (vv) sums over o -> atomics
#pragma unroll
    for (int ma = 0; ma < 2; ++ma)
#pragma unroll
        for (int r = 0; r < 4; ++r) {
#pragma unroll
            for (int msk = 1; msk < 16; msk <<= 1) {
                s2[ma][r] += __shfl_xor(s2[ma][r], msk);
                q2[ma][r] += __shfl_xor(q2[ma][r], msk);
            }
        }
    if (lx == 0) {
#pragma unroll
        for (int ma = 0; ma < 2; ++ma)
#pragma unroll
            for (int r = 0; r < 4; ++r) {
                r2S[wv][ma * 16 + g * 4 + r] = s2[ma][r];
                r2Q[wv][ma * 16 + g * 4 + r] = q2[ma][r];
            }
    }
    __syncthreads();
    if (tid < 32) {
        float ss = r2S[0][tid] + r2S[1][tid] + r2S[2][tid] + r2S[3][tid];
        float qq = r2Q[0][tid] + r2Q[1][tid] + r2Q[2][tid] + r2Q[3][tid];
        atomicAdd(&g2s[tid], ss);
        atomicAdd(&g2q[tid], qq);
    }
}

// ---------------- fc1: gbn2(norm+pool) fused on A-load, MFMA, relu -> fo1 fp32 ----------------
__global__ __launch_bounds__(256) void fc1_kernel(const float* __restrict__ ch2,
    const float* __restrict__ g2s, const float* __restrict__ g2q,
    const float* __restrict__ gg, const float* __restrict__ gb,
    const float* __restrict__ W, const float* __restrict__ bias, float* __restrict__ C)
{
    int n0 = blockIdx.x * 64;
    int tid = threadIdx.x, wv = tid >> 6, lane = tid & 63;
    int lx = lane & 15, g = lane >> 4;
    int wm = wv & 1, wn = wv >> 1;

    const float* w0 = W + (long)(n0 + wn * 32 + lx) * 2048 + g * 8;

    f32x4 acc[2][2] = {};
    for (int kstep = 0; kstep < 64; ++kstep) {
        int k = kstep * 32 + g * 8;
        int j = k >> 7, f0 = k & 127;
        float N2 = 8192.f;
        float m0_ = g2s[2 * j] / N2;
        float i0 = rsqrtf(g2q[2 * j] / N2 - m0_ * m0_ + 128.0f);
        float m1_ = g2s[2 * j + 1] / N2;
        float i1 = rsqrtf(g2q[2 * j + 1] / N2 - m1_ * m1_ + 128.0f);
        float sc0 = i0 * gg[2 * j], sh0 = gb[2 * j] - m0_ * sc0;
        float sc1 = i1 * gg[2 * j + 1], sh1 = gb[2 * j + 1] - m1_ * sc1;
        short8 af[2];
#pragma unroll
        for (int ma = 0; ma < 2; ++ma) {
            int b = wm * 32 + ma * 16 + lx;
            const float* p = ch2 + ((long)b * 32 + 2 * j) * 128 + f0;
            float4 x0 = *(const float4*)p;
            float4 x1 = *(const float4*)(p + 4);
            float4 y0 = *(const float4*)(p + 128);
            float4 y1 = *(const float4*)(p + 132);
            float4 r0, r1;
            r0.x = fmaxf(sc0 * x0.x + sh0, sc1 * y0.x + sh1);
            r0.y = fmaxf(sc0 * x0.y + sh0, sc1 * y0.y + sh1);
            r0.z = fmaxf(sc0 * x0.z + sh0, sc1 * y0.z + sh1);
            r0.w = fmaxf(sc0 * x0.w + sh0, sc1 * y0.w + sh1);
            r1.x = fmaxf(sc0 * x1.x + sh0, sc1 * y1.x + sh1);
            r1.y = fmaxf(sc0 * x1.y + sh0, sc1 * y1.y + sh1);
            r1.z = fmaxf(sc0 * x1.z + sh0, sc1 * y1.z + sh1);
            r1.w = fmaxf(sc0 * x1.w + sh0, sc1 * y1.w + sh1);
            af[ma] = cvt8(r0, r1);
        }
        short8 bf[2];
#pragma unroll
        for (int nb = 0; nb < 2; ++nb) {
            const float* wp = w0 + (long)nb * 16 * 2048 + kstep * 32;
            float4 x = *(const float4*)(wp);
            float4 y = *(const float4*)(wp + 4);
            bf[nb] = cvt8(x, y);
        }
#pragma unroll
        for (int ma = 0; ma < 2; ++ma)
#pragma unroll
            for (int nb = 0; nb < 2; ++nb)
                acc[ma][nb] = __builtin_amdgcn_mfma_f32_16x16x32_bf16(af[ma], bf[nb], acc[ma][nb], 0, 0, 0);
    }
#pragma unroll
    for (int ma = 0; ma < 2; ++ma)
#pragma unroll
        for (int nb = 0; nb < 2; ++nb) {
            int o = n0 + wn * 32 + nb * 16 + lx;
            float bia = bias[o];
#pragma unroll
            for (int r = 0; r < 4; ++r) {
                int b = wm * 32 + ma * 16 + g * 4 + r;
                C[(long)b * 512 + o] = fmaxf(acc[ma][nb][r] + bia, 0.f);
            }
        }
}

// ---------------- fc2 ----------------
__global__ void fc2_kernel(const float* __restrict__ x, const float* __restrict__ w,
                           const float* __restrict__ bv, float* __restrict__ out)
{
    int tid = threadIdx.x;   // 128 threads
    int b = tid >> 1, o = tid & 1;
    float acc = bv[o];
    for (int f = 0; f < 512; ++f) acc = fmaf(x[b * 512 + f], w[o * 512 + f], acc);
    out[tid] = acc;
}

// ---------------- launch ----------------
extern "C" void kernel_launch(void* const* d_in, const int* in_sizes, int n_in,
                              void* d_out, int out_size, void* d_ws, size_t ws_size,
                              hipStream_t stream)
{
    const float* inp    = (const float*)d_in[0];
    const float* L0     = (const float*)d_in[2];
    const float* L1m    = (const float*)d_in[3];
    const int*   lmax0  = (const int*)d_in[4];
    const int*   lmax1  = (const int*)d_in[5];
    const int*   perm   = (const int*)d_in[6];
    const float* conv1_w = (const float*)d_in[8];
    const float* conv1_b = (const float*)d_in[9];
    const float* bn1_g  = (const float*)d_in[10];
    const float* bn1_b  = (const float*)d_in[11];
    const float* conv2_w = (const float*)d_in[12];
    const float* conv2_b = (const float*)d_in[13];
    const float* bn2_g  = (const float*)d_in[14];
    const float* bn2_b  = (const float*)d_in[15];
    const float* lin1_w = (const float*)d_in[16];
    const float* lin1_b = (const float*)d_in[17];
    const float* cl1_w  = (const float*)d_in[18];
    const float* cl1_b  = (const float*)d_in[19];
    const float* gbn1_g = (const float*)d_in[20];
    const float* gbn1_b = (const float*)d_in[21];
    const float* cl2_w  = (const float*)d_in[22];
    const float* cl2_b  = (const float*)d_in[23];
    const float* gbn2_g = (const float*)d_in[24];
    const float* gbn2_b = (const float*)d_in[25];
    const float* fc1_w  = (const float*)d_in[26];
    const float* fc1_b  = (const float*)d_in[27];
    const float* fc2_w  = (const float*)d_in[28];
    const float* fc2_b  = (const float*)d_in[29];
    float* ws  = (float*)d_ws;
    char*  wsb = (char*)d_ws;
    float* out = (float*)d_out;

    unsigned short* w1rb = (unsigned short*)(wsb + W1RB_B);
    unsigned short* w2rb = (unsigned short*)(wsb + W2RB_B);
    unsigned short* w2b  = (unsigned short*)(wsb + W2B_B);
    unsigned short* p1b  = (unsigned short*)(wsb + P1B_B);
    unsigned short* y2b  = (unsigned short*)(wsb + Y2_B);
    unsigned short* qb   = (unsigned short*)(wsb + QB_B);
    float*          co   = (float*)(wsb + CO_B);
    unsigned short* xkb  = (unsigned short*)(wsb + XK_B);
    float*          ch1  = (float*)(wsb + CH1_B);
    float*          ch2  = (float*)(wsb + CH2_B);
    float*          fo1  = (float*)(wsb + FO1_B);
    float*          lr0  = (float*)(wsb + LR0_B);
    float*          lr1  = (float*)(wsb + LR1_B);

    // 1. fused prep + conv1 pass1 (512 conv blocks + 9045 prep blocks)
    k1_prep_conv1_kernel<<<9557, 256, 0, stream>>>(inp, conv1_w, conv1_b,
        L0, L1m, lmax0, lmax1, cl1_w, cl2_w, conv2_w, ws);

    // 2. conv1 pass2 -> p1b bf16
    conv1_p2_kernel<<<512, 256, 0, stream>>>(inp, conv1_w, conv1_b, bn1_g, bn1_b, ws, p1b);

    // 3. conv2 MFMA (M-tile 256) -> y2 bf16 + stats
    conv2_mfma_kernel<<<dim3(14, 64), 256, 0, stream>>>(p1b, w2b, conv2_b, y2b, ws + S2S, ws + S2Q);

    // 4. bn2 + pool (LDS transpose) -> qb bf16
    bn2_pool_kernel<<<4096, 256, 0, stream>>>(y2b, ws, bn2_g, bn2_b, qb);

    // 5. lin1 MFMA -> co fp32
    gemm_a16w32_kernel<<<dim3(8, 64), 256, 0, stream>>>(qb, lin1_w, lin1_b, co,
        LIN1K, 512, (long)64 * LIN1K, (long)512 * LIN1K, 512, (long)64 * 512);

    // 6. cheby layer 1 recursion (perm-gather + x0..x4, bf16 stores)
    rec_fused_kernel<<<256, 256, 0, stream>>>(lr0, co, perm, xkb);

    // 7. cheby1 MFMA output GEMM + gbn1 stats -> ch1 fp32
    cheby1_mfma_kernel<<<256, 256, 0, stream>>>(xkb, w1rb, cl1_b, ch1, ws + G1S, ws + G1Q);

    // 8. layer2: gbn1(norm+pool) fused + recursion + MFMA + gbn2 stats -> ch2 fp32
    layer2_kernel<<<64, 256, 0, stream>>>(ch1, ws + G1S, ws + G1Q, gbn1_g, gbn1_b,
        lr1, w2rb, cl2_b, ch2, ws + G2S, ws + G2Q);

    // 9. fc1: gbn2(norm+pool) fused on A-load, MFMA + relu -> fo1
    fc1_kernel<<<8, 256, 0, stream>>>(ch2, ws + G2S, ws + G2Q, gbn2_g, gbn2_b,
        fc1_w, fc1_b, fo1);

    // 10. fc2
    fc2_kernel<<<1, 128, 0, stream>>>(fo1, fc2_w, fc2_b, out);
}

// Round 7
// 360.642 us; speedup vs baseline: 1.0107x; 1.0107x over previous
//
#include <hip/hip_runtime.h>
#include <hip/hip_bf16.h>

typedef __attribute__((ext_vector_type(8))) short short8;
typedef __attribute__((ext_vector_type(4))) float f32x4;

// ---------------- constants ----------------
namespace {
constexpr int Bn  = 64;
constexpr int Cn  = 64;
constexpr int C1O = 32, C2O = 64;
constexpr int L1O = 249, L1P = 124;
constexpr int L2O = 55,  L2P = 27;
constexpr int LIN1K = C2O * L2P;      // 1728

// stats floats (zeroed region: idx < 8384)
constexpr long S2S = 0;          // 4096 conv2 sum
constexpr long S2Q = 4096;       // 4096 conv2 sumsq
constexpr long G1S = 8192;       // 64 gbn1 sum
constexpr long G1Q = 8256;       // 64 gbn1 sumsq
constexpr long G2S = 8320;       // 32 gbn2 sum
constexpr long G2Q = 8352;       // 32 gbn2 sumsq
constexpr long P1P = 8448;       // conv1 partials [2048 co][8 bg][2] = 32768 f (no init needed)

// byte offsets
constexpr long LR0_B  = 165888;      // 4096 f   -> 182272
constexpr long LR1_B  = 182272;      // 1024 f   -> 186368
constexpr long W1RB_B = 186368;      // 163840 bf16 -> 514048
constexpr long W2RB_B = 514048;      // 40960 bf16  -> 595968
constexpr long W2B_B  = 595968;      // 2097152 bf16 -> 4790272
constexpr long P1B_B  = 4790272;     // 16252928 bf16 -> 37296128
constexpr long Y2_B   = 37296128;    // 14417920 bf16 -> 66131968
constexpr long QB_B   = 94867456;    // 7077888 bf16 -> 109023232
constexpr long CO_B   = 109023232;   // 2097152 f -> 117411840
constexpr long XK_B   = 4790272;     // alias p1b/y2 (dead): 5*2097152 bf16 -> 25761792
constexpr long CH1_B  = 117411840;   // 262144 f -> 118460416
constexpr long CH2_B  = 118460416;   // 262144 f -> 119508992
constexpr long FO1_B  = 119508992;   // 32768 f
}

__device__ __forceinline__ unsigned short f2bf(float f) {
    union { float f; unsigned u; } v; v.f = f;
    unsigned r = v.u + 0x7FFFu + ((v.u >> 16) & 1u);
    return (unsigned short)(r >> 16);
}
__device__ __forceinline__ float bf2f(unsigned short s) {
    union { unsigned u; float f; } v; v.u = ((unsigned)s) << 16;
    return v.f;
}
__device__ __forceinline__ short8 cvt8(float4 a, float4 b) {
    float f[8] = {a.x, a.y, a.z, a.w, b.x, b.y, b.z, b.w};
    union { unsigned short s[8]; short8 v; } r;
#pragma unroll
    for (int i = 0; i < 8; ++i) r.s[i] = f2bf(f[i]);
    return r.v;
}
__device__ __forceinline__ uint2 pack4(float4 a) {
    union { unsigned short s[4]; uint2 u; } r;
    r.s[0] = f2bf(a.x); r.s[1] = f2bf(a.y); r.s[2] = f2bf(a.z); r.s[3] = f2bf(a.w);
    return r.u;
}

// ---------------- K1: fused prep + conv1 pass1 (partial stats, no atomics) ----------------
__global__ __launch_bounds__(256) void k1_prep_conv1_kernel(
    const float* __restrict__ inp, const float* __restrict__ w1, const float* __restrict__ b1,
    const float* __restrict__ L0, const float* __restrict__ L1m,
    const int* __restrict__ lmax0, const int* __restrict__ lmax1,
    const float* __restrict__ cl1w, const float* __restrict__ cl2w,
    const float* __restrict__ conv2w, float* __restrict__ ws)
{
    int bid = blockIdx.x;
    int tid = threadIdx.x;
    if (bid < 512) {
        // ---- conv1 pass1: block = (c, 8-batch group) ----
        int c = bid >> 3, bg = bid & 7;
        __shared__ float xs[8][512];
        __shared__ float rs[8][32], rq[8][32];
#pragma unroll
        for (int it = 0; it < 4; ++it) {
            int f4 = it * 256 + tid;
            int bl = f4 >> 7, off = (f4 & 127) * 4;
            *(float4*)&xs[bl][off] = *(const float4*)&inp[((long)(bg * 8 + bl) * 64 + c) * 512 + off];
        }
        int o = tid & 31, bq = tid >> 5;
        int co = c * 32 + o;
        float w[16];
#pragma unroll
        for (int t = 0; t < 16; ++t) w[t] = w1[co * 16 + t];
        float bias = b1[co];
        __syncthreads();
        float s = 0.f, q = 0.f;
        for (int jg = 0; jg < 31; ++jg) {
            float x[32];
#pragma unroll
            for (int h = 0; h < 8; ++h) *(float4*)&x[h * 4] = *(const float4*)&xs[bq][jg * 16 + h * 4];
#pragma unroll
            for (int j = 0; j < 8; ++j) {
                float a = bias;
#pragma unroll
                for (int t = 0; t < 16; ++t) a = fmaf(x[2 * j + t], w[t], a);
                a = fmaxf(a, 0.f);
                s += a; q += a * a;
            }
        }
        {   // l = 248
            float x[16];
#pragma unroll
            for (int h = 0; h < 4; ++h) *(float4*)&x[h * 4] = *(const float4*)&xs[bq][496 + h * 4];
            float a = bias;
#pragma unroll
            for (int t = 0; t < 16; ++t) a = fmaf(x[t], w[t], a);
            a = fmaxf(a, 0.f);
            s += a; q += a * a;
        }
        rs[bq][o] = s; rq[bq][o] = q;
        __syncthreads();
        if (tid < 32) {
            float ss = 0.f, qq = 0.f;
#pragma unroll
            for (int i = 0; i < 8; ++i) { ss += rs[i][tid]; qq += rq[i][tid]; }
            ws[P1P + (long)(c * 32 + tid) * 16 + bg * 2]     = ss;
            ws[P1P + (long)(c * 32 + tid) * 16 + bg * 2 + 1] = qq;
        }
    } else {
        // ---- prep ----
        long idx = (long)(bid - 512) * 256 + tid;
        float inv0 = 2.0f / (float)lmax0[0];
        float inv1 = 2.0f / (float)lmax1[0];
        char* wsb = (char*)ws;
        float* LR0p = (float*)(wsb + LR0_B);
        float* LR1p = (float*)(wsb + LR1_B);
        unsigned short* W1Rp = (unsigned short*)(wsb + W1RB_B);
        unsigned short* W2Rp = (unsigned short*)(wsb + W2RB_B);
        unsigned short* w2b  = (unsigned short*)(wsb + W2B_B);
        if (idx < 8384) {
            ws[idx] = 0.f;
        } else if (idx < 8384 + 4096) {
            long t = idx - 8384; int i = t / 64, j = t % 64;
            LR0p[t] = L0[t] * inv0 - (i == j ? 1.0f : 0.0f);
        } else if (idx < 8384 + 4096 + 1024) {
            long t = idx - 8384 - 4096; int i = t / 32, j = t % 32;
            LR1p[t] = L1m[t] * inv1 - (i == j ? 1.0f : 0.0f);
        } else if (idx < 8384 + 4096 + 1024 + 163840) {
            long t = idx - 8384 - 4096 - 1024;
            int k = t / 32768; int r = t % 32768; int o = r / 512, f = r % 512;
            W1Rp[t] = f2bf(cl1w[o * 2560 + f * 5 + k]);
        } else if (idx < 8384 + 4096 + 1024 + 163840 + 40960) {
            long t = idx - 8384 - 4096 - 1024 - 163840;
            int k = t / 8192; int r = t % 8192; int o = r / 64, f = r % 64;
            W2Rp[t] = f2bf(cl2w[o * 320 + f * 5 + k]);
        } else if (idx < 8384 + 4096 + 1024 + 163840 + 40960 + 2097152) {
            long t = idx - 8384 - 4096 - 1024 - 163840 - 40960;
            w2b[t] = f2bf(conv2w[t]);
        }
    }
}

// ---------------- conv1 pass2: conv+bn+pool -> p1b bf16 [c][b][o][124] ----------------
__global__ __launch_bounds__(256) void conv1_p2_kernel(const float* __restrict__ inp,
    const float* __restrict__ w1, const float* __restrict__ b1,
    const float* __restrict__ g, const float* __restrict__ be,
    const float* __restrict__ ws, unsigned short* __restrict__ p1)
{
    int c = blockIdx.x >> 3, bg = blockIdx.x & 7;
    __shared__ float xs[8][512];
    int tid = threadIdx.x;
#pragma unroll
    for (int it = 0; it < 4; ++it) {
        int f4 = it * 256 + tid;
        int bl = f4 >> 7, off = (f4 & 127) * 4;
        *(float4*)&xs[bl][off] = *(const float4*)&inp[((long)(bg * 8 + bl) * 64 + c) * 512 + off];
    }
    int o = tid & 31, bq = tid >> 5;
    int co = c * 32 + o;
    float w[16];
#pragma unroll
    for (int t = 0; t < 16; ++t) w[t] = w1[co * 16 + t];
    float bias = b1[co];
    float ssum = 0.f, qsum = 0.f;
#pragma unroll
    for (int i = 0; i < 8; ++i) {
        ssum += ws[P1P + (long)co * 16 + i * 2];
        qsum += ws[P1P + (long)co * 16 + i * 2 + 1];
    }
    float N = (float)(Bn * L1O);
    float m = ssum / N;
    float inv = rsqrtf(qsum / N - m * m + 1e-5f);
    float sc = inv * g[co], sh = be[co] - m * sc;
    __syncthreads();
    unsigned short* op = p1 + ((long)(c * 64 + bg * 8 + bq) * 32 + o) * 124;
    for (int jg = 0; jg < 31; ++jg) {
        float x[32];
#pragma unroll
        for (int h = 0; h < 8; ++h) *(float4*)&x[h * 4] = *(const float4*)&xs[bq][jg * 16 + h * 4];
        union { unsigned short r[4]; uint2 u; } pk;
#pragma unroll
        for (int p = 0; p < 4; ++p) {
            float a0 = bias, a1 = bias;
#pragma unroll
            for (int t = 0; t < 16; ++t) {
                a0 = fmaf(x[4 * p + t], w[t], a0);
                a1 = fmaf(x[4 * p + 2 + t], w[t], a1);
            }
            float v0 = fmaxf(a0, 0.f) * sc + sh;
            float v1 = fmaxf(a1, 0.f) * sc + sh;
            pk.r[p] = f2bf(fmaxf(v0, v1));
        }
        *(uint2*)&op[jg * 4] = pk.u;
    }
}

// ---------------- conv2 MFMA GEMM, M-tile 128 + relu + stats; y2 bf16 [c][b][l][o2] ----------------
__global__ __launch_bounds__(256) void conv2_mfma_kernel(const unsigned short* __restrict__ p1b,
    const unsigned short* __restrict__ w2b, const float* __restrict__ b2,
    unsigned short* __restrict__ y2b, float* __restrict__ s2s, float* __restrict__ s2q)
{
    int c = blockIdx.y;
    int m0 = blockIdx.x * 128;
    __shared__ unsigned short Bl[64 * 512];
    __shared__ float red[2][4][64];
    int tid = threadIdx.x;
    int w = tid >> 6, lane = tid & 63;
    int lx = lane & 15, g = lane >> 4;

    const unsigned short* wsrc = w2b + (long)c * 32768;
#pragma unroll
    for (int it = 0; it < 16; ++it) {
        int j = it * 256 + tid;
        int n = j >> 6, kb = j & 63;
        uint4 val = *(const uint4*)(wsrc + n * 512 + kb * 8);
        int dst = (n * 1024 + kb * 16) ^ ((n & 7) << 4);
        *(uint4*)((char*)Bl + dst) = val;
    }
    __syncthreads();

    const unsigned short* abase[2];
#pragma unroll
    for (int ma = 0; ma < 2; ++ma) {
        int m = m0 + w * 32 + ma * 16 + lx;
        m = min(m, 3519);
        int b = m / 55, lp = m % 55;
        abase[ma] = p1b + ((long)(c * 64 + b) * 32) * 124 + 2 * lp + (g & 1) * 8;
    }
    int cio = g >> 1;

    f32x4 acc[2][4] = {};
    for (int kstep = 0; kstep < 16; ++kstep) {
        short8 af[2];
#pragma unroll
        for (int ma = 0; ma < 2; ++ma) {
            const unsigned short* ap = abase[ma] + (kstep * 2 + cio) * 124;
            union { unsigned u[4]; short8 v; } t;
            t.u[0] = *(const unsigned*)(ap + 0);
            t.u[1] = *(const unsigned*)(ap + 2);
            t.u[2] = *(const unsigned*)(ap + 4);
            t.u[3] = *(const unsigned*)(ap + 6);
            af[ma] = t.v;
        }
#pragma unroll
        for (int fi = 0; fi < 4; ++fi) {
            int n = fi * 16 + lx;
            int off = (n * 1024 + kstep * 64 + g * 16) ^ ((n & 7) << 4);
            short8 bfrag = *(const short8*)((char*)Bl + off);
#pragma unroll
            for (int ma = 0; ma < 2; ++ma)
                acc[ma][fi] = __builtin_amdgcn_mfma_f32_16x16x32_bf16(af[ma], bfrag, acc[ma][fi], 0, 0, 0);
        }
    }

    float cs[4] = {}, cq[4] = {};
#pragma unroll
    for (int fi = 0; fi < 4; ++fi) {
        int o2 = fi * 16 + lx;
        float bia = b2[c * 64 + o2];
#pragma unroll
        for (int ma = 0; ma < 2; ++ma) {
#pragma unroll
            for (int r = 0; r < 4; ++r) {
                int mm = m0 + w * 32 + ma * 16 + g * 4 + r;
                if (mm < 3520) {
                    int bb = mm / 55, ll = mm % 55;
                    float y = fmaxf(acc[ma][fi][r] + bia, 0.f);
                    y2b[((long)(c * 64 + bb) * 55 + ll) * 64 + o2] = f2bf(y);
                    cs[fi] += y; cq[fi] += y * y;
                }
            }
        }
    }
#pragma unroll
    for (int fi = 0; fi < 4; ++fi) {
        cs[fi] += __shfl_xor(cs[fi], 16); cs[fi] += __shfl_xor(cs[fi], 32);
        cq[fi] += __shfl_xor(cq[fi], 16); cq[fi] += __shfl_xor(cq[fi], 32);
    }
    __syncthreads();
    if (g == 0) {
#pragma unroll
        for (int fi = 0; fi < 4; ++fi) { red[0][w][fi * 16 + lx] = cs[fi]; red[1][w][fi * 16 + lx] = cq[fi]; }
    }
    __syncthreads();
    if (tid < 64) {
        float ss = red[0][0][tid] + red[0][1][tid] + red[0][2][tid] + red[0][3][tid];
        float qq = red[1][0][tid] + red[1][1][tid] + red[1][2][tid] + red[1][3][tid];
        atomicAdd(&s2s[c * 64 + tid], ss);
        atomicAdd(&s2q[c * 64 + tid], qq);
    }
}

// ---------------- conv2 bn + pool via LDS transpose; block per (c,b) ----------------
__global__ __launch_bounds__(256) void bn2_pool_kernel(const unsigned short* __restrict__ y2b,
    const float* __restrict__ ws, const float* __restrict__ g, const float* __restrict__ be,
    unsigned short* __restrict__ q)
{
    int bid = blockIdx.x;              // c*64+b
    int c = bid >> 6;
    __shared__ unsigned short t2[55][66];
    const unsigned* src = (const unsigned*)(y2b + (long)bid * 3520);
    for (int i = threadIdx.x; i < 1760; i += 256) {
        int r = i >> 5, cu = i & 31;
        *(unsigned*)&t2[r][cu * 2] = src[i];
    }
    __syncthreads();
    float N = (float)(Bn * L2O);
    unsigned short* qp = q + (long)bid * 1728;
    for (int t = threadIdx.x; t < 1728; t += 256) {
        int o2 = t / 27, j = t - o2 * 27;
        int co = c * 64 + o2;
        float m = ws[S2S + co] / N;
        float inv = rsqrtf(ws[S2Q + co] / N - m * m + 1e-5f);
        float sc = inv * g[co], sh = be[co] - m * sc;
        float v = fmaxf(sc * bf2f(t2[2 * j][o2]) + sh, sc * bf2f(t2[2 * j + 1][o2]) + sh);
        qp[t] = f2bf(v);
    }
}

// ---------------- generic MFMA GEMM (lin1): C[64,Ntot] = relu(A_bf16[64,K] @ W_fp32[Ntot,K]^T + b) ----
__global__ __launch_bounds__(256) void gemm_a16w32_kernel(const unsigned short* __restrict__ A,
    const float* __restrict__ W, const float* __restrict__ bias, float* __restrict__ C,
    int K, int Ntot, long sA, long sW, long sB, long sC)
{
    int c = blockIdx.y;
    A += (long)c * sA; W += (long)c * sW; bias += (long)c * sB; C += (long)c * sC;
    int n0 = blockIdx.x * 64;
    int tid = threadIdx.x, wv = tid >> 6, lane = tid & 63;
    int lx = lane & 15, g = lane >> 4;
    int wm = wv & 1, wn = wv >> 1;

    const unsigned short* a0 = A + (long)(wm * 32 + lx) * K + g * 8;
    const float* w0 = W + (long)(n0 + wn * 32 + lx) * K + g * 8;
    int ksteps = K >> 5;

    f32x4 acc[2][2] = {};
    for (int kstep = 0; kstep < ksteps; ++kstep) {
        short8 af[2];
        af[0] = *(const short8*)(a0 + kstep * 32);
        af[1] = *(const short8*)(a0 + (long)16 * K + kstep * 32);
        short8 bf[2];
#pragma unroll
        for (int nb = 0; nb < 2; ++nb) {
            const float* wp = w0 + (long)nb * 16 * K + kstep * 32;
            float4 x = *(const float4*)(wp);
            float4 y = *(const float4*)(wp + 4);
            bf[nb] = cvt8(x, y);
        }
#pragma unroll
        for (int ma = 0; ma < 2; ++ma)
#pragma unroll
            for (int nb = 0; nb < 2; ++nb)
                acc[ma][nb] = __builtin_amdgcn_mfma_f32_16x16x32_bf16(af[ma], bf[nb], acc[ma][nb], 0, 0, 0);
    }
#pragma unroll
    for (int ma = 0; ma < 2; ++ma)
#pragma unroll
        for (int nb = 0; nb < 2; ++nb) {
            int o = n0 + wn * 32 + nb * 16 + lx;
            float bia = bias[o];
#pragma unroll
            for (int r = 0; r < 4; ++r) {
                int b = wm * 32 + ma * 16 + g * 4 + r;
                C[(long)b * Ntot + o] = fmaxf(acc[ma][nb][r] + bia, 0.f);
            }
        }
}

// ---------------- fused chebyshev recursion V=64: x0..x4, bf16 stores ----------------
__global__ __launch_bounds__(256) void rec_fused_kernel(const float* __restrict__ Lr,
    const float* __restrict__ co, const int* __restrict__ perm, unsigned short* __restrict__ xkb)
{
    __shared__ float Lt[64 * 64];     // Lt[u][v] = Lr[v][u]
    __shared__ float xA[64][130];
    __shared__ float xB[64][130];
    int tid = threadIdx.x;
    for (int i = tid; i < 4096; i += 256) Lt[(i & 63) * 64 + (i >> 6)] = Lr[i];
    int cg = tid & 31, vg = tid >> 5;
    int col = blockIdx.x * 128 + cg * 4;
#pragma unroll
    for (int i = 0; i < 8; ++i) {
        int v = vg * 8 + i;
        float4 x = *(const float4*)&co[(long)perm[v] * 32768 + col];
        *(float4*)&xA[v][cg * 4] = x;
        *(uint2*)&xkb[(long)v * 32768 + col] = pack4(x);
    }
    __syncthreads();
#pragma unroll
    for (int k = 1; k <= 4; ++k) {
        float (*prev)[130] = (k & 1) ? xA : xB;
        float (*dst)[130]  = (k & 1) ? xB : xA;
        float acc[8][4] = {};
        for (int u = 0; u < 64; ++u) {
            float4 xv = *(const float4*)&prev[u][cg * 4];
            float4 l0 = *(const float4*)&Lt[u * 64 + vg * 8];
            float4 l1 = *(const float4*)&Lt[u * 64 + vg * 8 + 4];
            float lv[8] = {l0.x, l0.y, l0.z, l0.w, l1.x, l1.y, l1.z, l1.w};
#pragma unroll
            for (int i = 0; i < 8; ++i) {
                acc[i][0] = fmaf(lv[i], xv.x, acc[i][0]);
                acc[i][1] = fmaf(lv[i], xv.y, acc[i][1]);
                acc[i][2] = fmaf(lv[i], xv.z, acc[i][2]);
                acc[i][3] = fmaf(lv[i], xv.w, acc[i][3]);
            }
        }
#pragma unroll
        for (int i = 0; i < 8; ++i) {
            int v = vg * 8 + i;
            float4 r;
            if (k == 1) {
                r.x = acc[i][0]; r.y = acc[i][1]; r.z = acc[i][2]; r.w = acc[i][3];
            } else {
                float4 p = *(const float4*)&dst[v][cg * 4];   // holds x_{k-2}
                r.x = 2.f * acc[i][0] - p.x; r.y = 2.f * acc[i][1] - p.y;
                r.z = 2.f * acc[i][2] - p.z; r.w = 2.f * acc[i][3] - p.w;
            }
            *(float4*)&dst[v][cg * 4] = r;
            *(uint2*)&xkb[(long)k * 2097152 + (long)v * 32768 + col] = pack4(r);
        }
        __syncthreads();
    }
}

// ---------------- cheby layer-1 output GEMM + gbn1 stats atomics ----------------
__global__ __launch_bounds__(256) void cheby1_mfma_kernel(const unsigned short* __restrict__ xkb,
    const unsigned short* __restrict__ w1rb, const float* __restrict__ bias,
    float* __restrict__ out, float* __restrict__ g1s, float* __restrict__ g1q)
{
    int m0 = blockIdx.x * 16;
    __shared__ unsigned short Bl[64 * 512];
    __shared__ float rS[4][16], rQ[4][16];
    int tid = threadIdx.x, wv = tid >> 6, lane = tid & 63;
    int lx = lane & 15, g = lane >> 4;
    int m = m0 + lx;
    int v = m & 63, b = m >> 6;

    f32x4 acc = {};
    for (int kc = 0; kc < 5; ++kc) {
        __syncthreads();
#pragma unroll
        for (int it = 0; it < 16; ++it) {
            int j = it * 256 + tid;
            int n = j >> 6, kb = j & 63;
            uint4 val = *(const uint4*)(w1rb + (long)kc * 32768 + n * 512 + kb * 8);
            int dst = (n * 1024 + kb * 16) ^ ((n & 7) << 4);
            *(uint4*)((char*)Bl + dst) = val;
        }
        __syncthreads();
        const unsigned short* ab = xkb + (long)(kc * 64 + v) * 32768 + b * 512 + g * 8;
        for (int kl = 0; kl < 16; ++kl) {
            short8 af = *(const short8*)(ab + kl * 32);
            int n = wv * 16 + lx;
            int off = (n * 1024 + kl * 64 + g * 16) ^ ((n & 7) << 4);
            short8 bfrag = *(const short8*)((char*)Bl + off);
            acc = __builtin_amdgcn_mfma_f32_16x16x32_bf16(af, bfrag, acc, 0, 0, 0);
        }
    }
    int o = wv * 16 + lx;
    float bia = bias[o];
    float sv[4], qv[4];
#pragma unroll
    for (int r = 0; r < 4; ++r) {
        int mm = m0 + g * 4 + r;
        int vv = mm & 63, bb = mm >> 6;
        float val = fmaxf(acc[r] + bia, 0.f);
        out[((long)(bb * 64 + vv)) * 64 + o] = val;
        sv[r] = val; qv[r] = val * val;
    }
    // gbn1 stats: per-row sums (over o) -> atomics per v
#pragma unroll
    for (int r = 0; r < 4; ++r) {
#pragma unroll
        for (int msk = 1; msk < 16; msk <<= 1) {
            sv[r] += __shfl_xor(sv[r], msk);
            qv[r] += __shfl_xor(qv[r], msk);
        }
    }
    if (lx == 0) {
#pragma unroll
        for (int r = 0; r < 4; ++r) { rS[wv][g * 4 + r] = sv[r]; rQ[wv][g * 4 + r] = qv[r]; }
    }
    __syncthreads();
    if (tid < 16) {
        float ss = rS[0][tid] + rS[1][tid] + rS[2][tid] + rS[3][tid];
        float qq = rQ[0][tid] + rQ[1][tid] + rQ[2][tid] + rQ[3][tid];
        int vv = (m0 + tid) & 63;
        atomicAdd(&g1s[vv], ss);
        atomicAdd(&g1q[vv], qq);
    }
}

// ---------------- fused layer 2: gbn1(norm+pool) on load + cheby rec + MFMA + gbn2 stats ----------------
__global__ __launch_bounds__(256) void layer2_kernel(const float* __restrict__ ch1,
    const float* __restrict__ g1s, const float* __restrict__ g1q,
    const float* __restrict__ gbn1g, const float* __restrict__ gbn1b,
    const float* __restrict__ Lr1, const unsigned short* __restrict__ w2rb,
    const float* __restrict__ bias, float* __restrict__ out,
    float* __restrict__ g2s, float* __restrict__ g2q)
{
    int b = blockIdx.x;
    __shared__ float xs[5][32][72];
    __shared__ unsigned short wsl[128 * 320];
    __shared__ float r2S[4][32], r2Q[4][32];
    int tid = threadIdx.x;
#pragma unroll
    for (int it = 0; it < 20; ++it) {
        int j = it * 256 + tid;
        int o = j / 40, kb = j % 40;
        uint4 val = *(const uint4*)(w2rb + ((long)(kb >> 3) * 128 + o) * 64 + (kb & 7) * 8);
        int dst = (o * 640 + kb * 16) ^ ((o & 7) << 4);
        *(uint4*)((char*)wsl + dst) = val;
    }
    int v = tid & 31, fg = tid >> 5;
    float lrow[32];
#pragma unroll
    for (int u = 0; u < 32; ++u) lrow[u] = Lr1[v * 32 + u];
    {
        // fused gbn1 normalize + gpool: xs[0][v][f] from ch1[b][2v / 2v+1][f]
        float N1 = 4096.f;
        float mA = g1s[2 * v] / N1;
        float iA = rsqrtf(g1q[2 * v] / N1 - mA * mA + 64.0f);
        float mB = g1s[2 * v + 1] / N1;
        float iB = rsqrtf(g1q[2 * v + 1] / N1 - mB * mB + 64.0f);
        float sc0 = iA * gbn1g[2 * v], sh0 = gbn1b[2 * v] - mA * sc0;
        float sc1 = iB * gbn1g[2 * v + 1], sh1 = gbn1b[2 * v + 1] - mB * sc1;
        const float* c0 = ch1 + ((long)b * 64 + 2 * v) * 64 + fg * 8;
        float4 a0 = *(const float4*)c0;
        float4 a1 = *(const float4*)(c0 + 4);
        float4 b0 = *(const float4*)(c0 + 64);
        float4 b1 = *(const float4*)(c0 + 68);
        float4 r0, r1;
        r0.x = fmaxf(sc0 * a0.x + sh0, sc1 * b0.x + sh1);
        r0.y = fmaxf(sc0 * a0.y + sh0, sc1 * b0.y + sh1);
        r0.z = fmaxf(sc0 * a0.z + sh0, sc1 * b0.z + sh1);
        r0.w = fmaxf(sc0 * a0.w + sh0, sc1 * b0.w + sh1);
        r1.x = fmaxf(sc0 * a1.x + sh0, sc1 * b1.x + sh1);
        r1.y = fmaxf(sc0 * a1.y + sh0, sc1 * b1.y + sh1);
        r1.z = fmaxf(sc0 * a1.z + sh0, sc1 * b1.z + sh1);
        r1.w = fmaxf(sc0 * a1.w + sh0, sc1 * b1.w + sh1);
        *(float4*)&xs[0][v][fg * 8] = r0;
        *(float4*)&xs[0][v][fg * 8 + 4] = r1;
    }
    __syncthreads();
    for (int k = 1; k < 5; ++k) {
        float acc[8] = {};
#pragma unroll
        for (int u = 0; u < 32; ++u) {
            float4 xa = *(const float4*)&xs[k - 1][u][fg * 8];
            float4 xb = *(const float4*)&xs[k - 1][u][fg * 8 + 4];
            float l = lrow[u];
            acc[0] = fmaf(l, xa.x, acc[0]); acc[1] = fmaf(l, xa.y, acc[1]);
            acc[2] = fmaf(l, xa.z, acc[2]); acc[3] = fmaf(l, xa.w, acc[3]);
            acc[4] = fmaf(l, xb.x, acc[4]); acc[5] = fmaf(l, xb.y, acc[5]);
            acc[6] = fmaf(l, xb.z, acc[6]); acc[7] = fmaf(l, xb.w, acc[7]);
        }
        float4 ra, rb;
        if (k >= 2) {
            float4 pa = *(const float4*)&xs[k - 2][v][fg * 8];
            float4 pb = *(const float4*)&xs[k - 2][v][fg * 8 + 4];
            ra.x = 2.f * acc[0] - pa.x; ra.y = 2.f * acc[1] - pa.y;
            ra.z = 2.f * acc[2] - pa.z; ra.w = 2.f * acc[3] - pa.w;
            rb.x = 2.f * acc[4] - pb.x; rb.y = 2.f * acc[5] - pb.y;
            rb.z = 2.f * acc[6] - pb.z; rb.w = 2.f * acc[7] - pb.w;
        } else {
            ra.x = acc[0]; ra.y = acc[1]; ra.z = acc[2]; ra.w = acc[3];
            rb.x = acc[4]; rb.y = acc[5]; rb.z = acc[6]; rb.w = acc[7];
        }
        *(float4*)&xs[k][v][fg * 8] = ra;
        *(float4*)&xs[k][v][fg * 8 + 4] = rb;
        __syncthreads();
    }
    int wv = tid >> 6, lane = tid & 63;
    int lx = lane & 15, g = lane >> 4;
    f32x4 acc2[2][2] = {};
    for (int kstep = 0; kstep < 10; ++kstep) {
        int k = kstep * 32 + g * 8;
        int kc = k >> 6, f = k & 63;
        short8 af[2];
#pragma unroll
        for (int ma = 0; ma < 2; ++ma) {
            int vv = ma * 16 + lx;
            float4 xa = *(const float4*)&xs[kc][vv][f];
            float4 xb = *(const float4*)&xs[kc][vv][f + 4];
            af[ma] = cvt8(xa, xb);
        }
#pragma unroll
        for (int nb = 0; nb < 2; ++nb) {
            int o = wv * 32 + nb * 16 + lx;
            int kb = kstep * 4 + g;
            int off = (o * 640 + kb * 16) ^ ((o & 7) << 4);
            short8 bf = *(const short8*)((char*)wsl + off);
#pragma unroll
            for (int ma = 0; ma < 2; ++ma)
                acc2[ma][nb] = __builtin_amdgcn_mfma_f32_16x16x32_bf16(af[ma], bf, acc2[ma][nb], 0, 0, 0);
        }
    }
    float s2[2][4] = {}, q2[2][4] = {};
#pragma unroll
    for (int ma = 0; ma < 2; ++ma)
#pragma unroll
        for (int nb = 0; nb < 2; ++nb) {
            int o = wv * 32 + nb * 16 + lx;
            float bia = bias[o];
#pragma unroll
            for (int r = 0; r < 4; ++r) {
                int vv = ma * 16 + g * 4 + r;
                float val = fmaxf(acc2[ma][nb][r] + bia, 0.f);
                out[((long)b * 32 + vv) * 128 + o] = val;
                s2[ma][r] += val; q2[ma][r] += val * val;
            }
        }
    // gbn2 stats: per-row (vv) sums over o -> atomics
#pragma unroll
    for (int ma = 0; ma < 2; ++ma)
#pragma unroll
        for (int r = 0; r < 4; ++r) {
#pragma unroll
            for (int msk = 1; msk < 16; msk <<= 1) {
                s2[ma][r] += __shfl_xor(s2[ma][r], msk);
                q2[ma][r] += __shfl_xor(q2[ma][r], msk);
            }
        }
    if (lx == 0) {
#pragma unroll
        for (int ma = 0; ma < 2; ++ma)
#pragma unroll
            for (int r = 0; r < 4; ++r) {
                r2S[wv][ma * 16 + g * 4 + r] = s2[ma][r];
                r2Q[wv][ma * 16 + g * 4 + r] = q2[ma][r];
            }
    }
    __syncthreads();
    if (tid < 32) {
        float ss = r2S[0][tid] + r2S[1][tid] + r2S[2][tid] + r2S[3][tid];
        float qq = r2Q[0][tid] + r2Q[1][tid] + r2Q[2][tid] + r2Q[3][tid];
        atomicAdd(&g2s[tid], ss);
        atomicAdd(&g2q[tid], qq);
    }
}

// ---------------- fc1: gbn2(norm+pool) fused on A-load, MFMA, relu -> fo1 fp32 ----------------
__global__ __launch_bounds__(256) void fc1_kernel(const float* __restrict__ ch2,
    const float* __restrict__ g2s, const float* __restrict__ g2q,
    const float* __restrict__ gg, const float* __restrict__ gb,
    const float* __restrict__ W, const float* __restrict__ bias, float* __restrict__ C)
{
    int n0 = blockIdx.x * 64;
    int tid = threadIdx.x, wv = tid >> 6, lane = tid & 63;
    int lx = lane & 15, g = lane >> 4;
    int wm = wv & 1, wn = wv >> 1;

    const float* w0 = W + (long)(n0 + wn * 32 + lx) * 2048 + g * 8;

    f32x4 acc[2][2] = {};
    for (int kstep = 0; kstep < 64; ++kstep) {
        int k = kstep * 32 + g * 8;
        int j = k >> 7, f0 = k & 127;
        float N2 = 8192.f;
        float m0_ = g2s[2 * j] / N2;
        float i0 = rsqrtf(g2q[2 * j] / N2 - m0_ * m0_ + 128.0f);
        float m1_ = g2s[2 * j + 1] / N2;
        float i1 = rsqrtf(g2q[2 * j + 1] / N2 - m1_ * m1_ + 128.0f);
        float sc0 = i0 * gg[2 * j], sh0 = gb[2 * j] - m0_ * sc0;
        float sc1 = i1 * gg[2 * j + 1], sh1 = gb[2 * j + 1] - m1_ * sc1;
        short8 af[2];
#pragma unroll
        for (int ma = 0; ma < 2; ++ma) {
            int b = wm * 32 + ma * 16 + lx;
            const float* p = ch2 + ((long)b * 32 + 2 * j) * 128 + f0;
            float4 x0 = *(const float4*)p;
            float4 x1 = *(const float4*)(p + 4);
            float4 y0 = *(const float4*)(p + 128);
            float4 y1 = *(const float4*)(p + 132);
            float4 r0, r1;
            r0.x = fmaxf(sc0 * x0.x + sh0, sc1 * y0.x + sh1);
            r0.y = fmaxf(sc0 * x0.y + sh0, sc1 * y0.y + sh1);
            r0.z = fmaxf(sc0 * x0.z + sh0, sc1 * y0.z + sh1);
            r0.w = fmaxf(sc0 * x0.w + sh0, sc1 * y0.w + sh1);
            r1.x = fmaxf(sc0 * x1.x + sh0, sc1 * y1.x + sh1);
            r1.y = fmaxf(sc0 * x1.y + sh0, sc1 * y1.y + sh1);
            r1.z = fmaxf(sc0 * x1.z + sh0, sc1 * y1.z + sh1);
            r1.w = fmaxf(sc0 * x1.w + sh0, sc1 * y1.w + sh1);
            af[ma] = cvt8(r0, r1);
        }
        short8 bf[2];
#pragma unroll
        for (int nb = 0; nb < 2; ++nb) {
            const float* wp = w0 + (long)nb * 16 * 2048 + kstep * 32;
            float4 x = *(const float4*)(wp);
            float4 y = *(const float4*)(wp + 4);
            bf[nb] = cvt8(x, y);
        }
#pragma unroll
        for (int ma = 0; ma < 2; ++ma)
#pragma unroll
            for (int nb = 0; nb < 2; ++nb)
                acc[ma][nb] = __builtin_amdgcn_mfma_f32_16x16x32_bf16(af[ma], bf[nb], acc[ma][nb], 0, 0, 0);
    }
#pragma unroll
    for (int ma = 0; ma < 2; ++ma)
#pragma unroll
        for (int nb = 0; nb < 2; ++nb) {
            int o = n0 + wn * 32 + nb * 16 + lx;
            float bia = bias[o];
#pragma unroll
            for (int r = 0; r < 4; ++r) {
                int b = wm * 32 + ma * 16 + g * 4 + r;
                C[(long)b * 512 + o] = fmaxf(acc[ma][nb][r] + bia, 0.f);
            }
        }
}

// ---------------- fc2 ----------------
__global__ void fc2_kernel(const float* __restrict__ x, const float* __restrict__ w,
                           const float* __restrict__ bv, float* __restrict__ out)
{
    int tid = threadIdx.x;   // 128 threads
    int b = tid >> 1, o = tid & 1;
    float acc = bv[o];
    for (int f = 0; f < 512; ++f) acc = fmaf(x[b * 512 + f], w[o * 512 + f], acc);
    out[tid] = acc;
}

// ---------------- launch ----------------
extern "C" void kernel_launch(void* const* d_in, const int* in_sizes, int n_in,
                              void* d_out, int out_size, void* d_ws, size_t ws_size,
                              hipStream_t stream)
{
    const float* inp    = (const float*)d_in[0];
    const float* L0     = (const float*)d_in[2];
    const float* L1m    = (const float*)d_in[3];
    const int*   lmax0  = (const int*)d_in[4];
    const int*   lmax1  = (const int*)d_in[5];
    const int*   perm   = (const int*)d_in[6];
    const float* conv1_w = (const float*)d_in[8];
    const float* conv1_b = (const float*)d_in[9];
    const float* bn1_g  = (const float*)d_in[10];
    const float* bn1_b  = (const float*)d_in[11];
    const float* conv2_w = (const float*)d_in[12];
    const float* conv2_b = (const float*)d_in[13];
    const float* bn2_g  = (const float*)d_in[14];
    const float* bn2_b  = (const float*)d_in[15];
    const float* lin1_w = (const float*)d_in[16];
    const float* lin1_b = (const float*)d_in[17];
    const float* cl1_w  = (const float*)d_in[18];
    const float* cl1_b  = (const float*)d_in[19];
    const float* gbn1_g = (const float*)d_in[20];
    const float* gbn1_b = (const float*)d_in[21];
    const float* cl2_w  = (const float*)d_in[22];
    const float* cl2_b  = (const float*)d_in[23];
    const float* gbn2_g = (const float*)d_in[24];
    const float* gbn2_b = (const float*)d_in[25];
    const float* fc1_w  = (const float*)d_in[26];
    const float* fc1_b  = (const float*)d_in[27];
    const float* fc2_w  = (const float*)d_in[28];
    const float* fc2_b  = (const float*)d_in[29];
    float* ws  = (float*)d_ws;
    char*  wsb = (char*)d_ws;
    float* out = (float*)d_out;

    unsigned short* w1rb = (unsigned short*)(wsb + W1RB_B);
    unsigned short* w2rb = (unsigned short*)(wsb + W2RB_B);
    unsigned short* w2b  = (unsigned short*)(wsb + W2B_B);
    unsigned short* p1b  = (unsigned short*)(wsb + P1B_B);
    unsigned short* y2b  = (unsigned short*)(wsb + Y2_B);
    unsigned short* qb   = (unsigned short*)(wsb + QB_B);
    float*          co   = (float*)(wsb + CO_B);
    unsigned short* xkb  = (unsigned short*)(wsb + XK_B);
    float*          ch1  = (float*)(wsb + CH1_B);
    float*          ch2  = (float*)(wsb + CH2_B);
    float*          fo1  = (float*)(wsb + FO1_B);
    float*          lr0  = (float*)(wsb + LR0_B);
    float*          lr1  = (float*)(wsb + LR1_B);

    // 1. fused prep + conv1 pass1 (512 conv blocks + 9045 prep blocks)
    k1_prep_conv1_kernel<<<9557, 256, 0, stream>>>(inp, conv1_w, conv1_b,
        L0, L1m, lmax0, lmax1, cl1_w, cl2_w, conv2_w, ws);

    // 2. conv1 pass2 -> p1b bf16
    conv1_p2_kernel<<<512, 256, 0, stream>>>(inp, conv1_w, conv1_b, bn1_g, bn1_b, ws, p1b);

    // 3. conv2 MFMA (M-tile 128) -> y2 bf16 + stats
    conv2_mfma_kernel<<<dim3(28, 64), 256, 0, stream>>>(p1b, w2b, conv2_b, y2b, ws + S2S, ws + S2Q);

    // 4. bn2 + pool (LDS transpose) -> qb bf16
    bn2_pool_kernel<<<4096, 256, 0, stream>>>(y2b, ws, bn2_g, bn2_b, qb);

    // 5. lin1 MFMA -> co fp32
    gemm_a16w32_kernel<<<dim3(8, 64), 256, 0, stream>>>(qb, lin1_w, lin1_b, co,
        LIN1K, 512, (long)64 * LIN1K, (long)512 * LIN1K, 512, (long)64 * 512);

    // 6. cheby layer 1 recursion (perm-gather + x0..x4, bf16 stores)
    rec_fused_kernel<<<256, 256, 0, stream>>>(lr0, co, perm, xkb);

    // 7. cheby1 MFMA output GEMM + gbn1 stats -> ch1 fp32
    cheby1_mfma_kernel<<<256, 256, 0, stream>>>(xkb, w1rb, cl1_b, ch1, ws + G1S, ws + G1Q);

    // 8. layer2: gbn1(norm+pool) fused + recursion + MFMA + gbn2 stats -> ch2 fp32
    layer2_kernel<<<64, 256, 0, stream>>>(ch1, ws + G1S, ws + G1Q, gbn1_g, gbn1_b,
        lr1, w2rb, cl2_b, ch2, ws + G2S, ws + G2Q);

    // 9. fc1: gbn2(norm+pool) fused on A-load, MFMA + relu -> fo1
    fc1_kernel<<<8, 256, 0, stream>>>(ch2, ws + G2S, ws + G2Q, gbn2_g, gbn2_b,
        fc1_w, fc1_b, fo1);

    // 10. fc2
    fc2_kernel<<<1, 128, 0, stream>>>(fo1, fc2_w, fc2_b, out);
}

// Round 8
// 347.496 us; speedup vs baseline: 1.0489x; 1.0378x over previous
//
#include <hip/hip_runtime.h>
#include <hip/hip_bf16.h>

typedef __attribute__((ext_vector_type(8))) short short8;
typedef __attribute__((ext_vector_type(4))) float f32x4;

// ---------------- constants ----------------
namespace {
constexpr int Bn  = 64;
constexpr int Cn  = 64;
constexpr int C1O = 32, C2O = 64;
constexpr int L1O = 249, L1P = 124;
constexpr int L2O = 55,  L2P = 27;
constexpr int FIN1 = 512;
constexpr int LIN1K = C2O * L2P;      // 1728

// stats floats
constexpr long S1S = 0;          // 2048 conv1 sum
constexpr long S1Q = 2048;       // 2048 conv1 sumsq
constexpr long S2S = 4096;       // 4096 conv2 sum
constexpr long S2Q = 8192;       // 4096 conv2 sumsq   (all zeroed by prep)

// byte offsets
constexpr long LR0_B  = 65536;       // 4096 f
constexpr long LR1_B  = 81920;       // 1024 f
constexpr long W1RB_B = 86016;       // 163840 bf16
constexpr long W2RB_B = 413696;      // 40960 bf16
constexpr long W2B_B  = 495616;      // 2097152 bf16 -> 4689920
constexpr long P1B_B  = 4689920;     // 16252928 bf16 -> 37195776
constexpr long Y2_B   = 37195776;    // 14417920 bf16 -> 66031616
constexpr long QB_B   = 94867456;    // 7077888 bf16
constexpr long CO_B   = 109023232;   // 2097152 f
constexpr long XK_B   = 4689920;     // alias p1b/y2 (dead): 5*2097152 bf16 -> 25661440
constexpr long CH1_B  = 117411840;   // 262144 f
constexpr long X2K_B  = 118460416;   // 131072 f
constexpr long CH2_B  = 118984704;   // 262144 f
constexpr long FCI_B  = 120033280;   // 131072 bf16
constexpr long FO1_B  = 120295424;   // 32768 f
}

__device__ __forceinline__ unsigned short f2bf(float f) {
    union { float f; unsigned u; } v; v.f = f;
    unsigned r = v.u + 0x7FFFu + ((v.u >> 16) & 1u);
    return (unsigned short)(r >> 16);
}
__device__ __forceinline__ float bf2f(unsigned short s) {
    union { unsigned u; float f; } v; v.u = ((unsigned)s) << 16;
    return v.f;
}
__device__ __forceinline__ short8 cvt8(float4 a, float4 b) {
    float f[8] = {a.x, a.y, a.z, a.w, b.x, b.y, b.z, b.w};
    union { unsigned short s[8]; short8 v; } r;
#pragma unroll
    for (int i = 0; i < 8; ++i) r.s[i] = f2bf(f[i]);
    return r.v;
}
__device__ __forceinline__ uint2 pack4(float4 a) {
    union { unsigned short s[4]; uint2 u; } r;
    r.s[0] = f2bf(a.x); r.s[1] = f2bf(a.y); r.s[2] = f2bf(a.z); r.s[3] = f2bf(a.w);
    return r.u;
}

// ---------------- prep: zero stats + Lr + cheby bf16 repacks + conv2_w bf16 ----------------
__global__ void prep_kernel(const float* __restrict__ L0, const float* __restrict__ L1m,
                            const int* __restrict__ lmax0, const int* __restrict__ lmax1,
                            const float* __restrict__ cl1w, const float* __restrict__ cl2w,
                            const float* __restrict__ conv2w, float* __restrict__ ws)
{
    long idx = (long)blockIdx.x * 256 + threadIdx.x;
    float inv0 = 2.0f / (float)lmax0[0];
    float inv1 = 2.0f / (float)lmax1[0];
    char* wsb = (char*)ws;
    float* LR0p = (float*)(wsb + LR0_B);
    float* LR1p = (float*)(wsb + LR1_B);
    unsigned short* W1Rp = (unsigned short*)(wsb + W1RB_B);
    unsigned short* W2Rp = (unsigned short*)(wsb + W2RB_B);
    unsigned short* w2b  = (unsigned short*)(wsb + W2B_B);
    if (idx < 12288) {
        ws[idx] = 0.f;
    } else if (idx < 12288 + 4096) {
        long t = idx - 12288; int i = t / 64, j = t % 64;
        LR0p[t] = L0[t] * inv0 - (i == j ? 1.0f : 0.0f);
    } else if (idx < 12288 + 4096 + 1024) {
        long t = idx - 12288 - 4096; int i = t / 32, j = t % 32;
        LR1p[t] = L1m[t] * inv1 - (i == j ? 1.0f : 0.0f);
    } else if (idx < 12288 + 4096 + 1024 + 163840) {
        long t = idx - 12288 - 4096 - 1024;
        int k = t / 32768; int r = t % 32768; int o = r / 512, f = r % 512;
        W1Rp[t] = f2bf(cl1w[o * 2560 + f * 5 + k]);
    } else if (idx < 12288 + 4096 + 1024 + 163840 + 40960) {
        long t = idx - 12288 - 4096 - 1024 - 163840;
        int k = t / 8192; int r = t % 8192; int o = r / 64, f = r % 64;
        W2Rp[t] = f2bf(cl2w[o * 320 + f * 5 + k]);
    } else if (idx < 12288 + 4096 + 1024 + 163840 + 40960 + 2097152) {
        long t = idx - 12288 - 4096 - 1024 - 163840 - 40960;
        w2b[t] = f2bf(conv2w[t]);
    }
}

// ---------------- conv1 pass1: conv+relu+stats; block = (c, 8-batch group) ----------------
__global__ __launch_bounds__(256) void conv1_p1_kernel(const float* __restrict__ inp,
    const float* __restrict__ w1, const float* __restrict__ b1, float* __restrict__ ws)
{
    int c = blockIdx.x >> 3, bg = blockIdx.x & 7;
    __shared__ float xs[8][512];
    __shared__ float rs[8][32], rq[8][32];
    int tid = threadIdx.x;
#pragma unroll
    for (int it = 0; it < 4; ++it) {
        int f4 = it * 256 + tid;
        int bl = f4 >> 7, off = (f4 & 127) * 4;
        *(float4*)&xs[bl][off] = *(const float4*)&inp[((long)(bg * 8 + bl) * 64 + c) * 512 + off];
    }
    int o = tid & 31, bq = tid >> 5;
    int co = c * 32 + o;
    float w[16];
#pragma unroll
    for (int t = 0; t < 16; ++t) w[t] = w1[co * 16 + t];
    float bias = b1[co];
    __syncthreads();
    float s = 0.f, q = 0.f;
    for (int jg = 0; jg < 31; ++jg) {
        float x[32];
#pragma unroll
        for (int h = 0; h < 8; ++h) *(float4*)&x[h * 4] = *(const float4*)&xs[bq][jg * 16 + h * 4];
#pragma unroll
        for (int j = 0; j < 8; ++j) {
            float a = bias;
#pragma unroll
            for (int t = 0; t < 16; ++t) a = fmaf(x[2 * j + t], w[t], a);
            a = fmaxf(a, 0.f);
            s += a; q += a * a;
        }
    }
    {   // l = 248
        float x[16];
#pragma unroll
        for (int h = 0; h < 4; ++h) *(float4*)&x[h * 4] = *(const float4*)&xs[bq][496 + h * 4];
        float a = bias;
#pragma unroll
        for (int t = 0; t < 16; ++t) a = fmaf(x[t], w[t], a);
        a = fmaxf(a, 0.f);
        s += a; q += a * a;
    }
    rs[bq][o] = s; rq[bq][o] = q;
    __syncthreads();
    if (tid < 32) {
        float ss = 0.f, qq = 0.f;
#pragma unroll
        for (int i = 0; i < 8; ++i) { ss += rs[i][tid]; qq += rq[i][tid]; }
        atomicAdd(&ws[S1S + c * 32 + tid], ss);
        atomicAdd(&ws[S1Q + c * 32 + tid], qq);
    }
}

// ---------------- conv1 pass2: conv+bn+pool -> p1b bf16 [c][b][o][124] ----------------
__global__ __launch_bounds__(256) void conv1_p2_kernel(const float* __restrict__ inp,
    const float* __restrict__ w1, const float* __restrict__ b1,
    const float* __restrict__ g, const float* __restrict__ be,
    const float* __restrict__ ws, unsigned short* __restrict__ p1)
{
    int c = blockIdx.x >> 3, bg = blockIdx.x & 7;
    __shared__ float xs[8][512];
    int tid = threadIdx.x;
#pragma unroll
    for (int it = 0; it < 4; ++it) {
        int f4 = it * 256 + tid;
        int bl = f4 >> 7, off = (f4 & 127) * 4;
        *(float4*)&xs[bl][off] = *(const float4*)&inp[((long)(bg * 8 + bl) * 64 + c) * 512 + off];
    }
    int o = tid & 31, bq = tid >> 5;
    int co = c * 32 + o;
    float w[16];
#pragma unroll
    for (int t = 0; t < 16; ++t) w[t] = w1[co * 16 + t];
    float bias = b1[co];
    float N = (float)(Bn * L1O);
    float m = ws[S1S + co] / N;
    float inv = rsqrtf(ws[S1Q + co] / N - m * m + 1e-5f);
    float sc = inv * g[co], sh = be[co] - m * sc;
    __syncthreads();
    unsigned short* op = p1 + ((long)(c * 64 + bg * 8 + bq) * 32 + o) * 124;
    for (int jg = 0; jg < 31; ++jg) {
        float x[32];
#pragma unroll
        for (int h = 0; h < 8; ++h) *(float4*)&x[h * 4] = *(const float4*)&xs[bq][jg * 16 + h * 4];
        union { unsigned short r[4]; uint2 u; } pk;
#pragma unroll
        for (int p = 0; p < 4; ++p) {
            float a0 = bias, a1 = bias;
#pragma unroll
            for (int t = 0; t < 16; ++t) {
                a0 = fmaf(x[4 * p + t], w[t], a0);
                a1 = fmaf(x[4 * p + 2 + t], w[t], a1);
            }
            float v0 = fmaxf(a0, 0.f) * sc + sh;
            float v1 = fmaxf(a1, 0.f) * sc + sh;
            pk.r[p] = f2bf(fmaxf(v0, v1));
        }
        *(uint2*)&op[jg * 4] = pk.u;
    }
}

// ---------------- conv2 MFMA GEMM, M-tile 128 + relu + stats; y2 bf16 [c][b][l][o2] ----------------
__global__ __launch_bounds__(256) void conv2_mfma_kernel(const unsigned short* __restrict__ p1b,
    const unsigned short* __restrict__ w2b, const float* __restrict__ b2,
    unsigned short* __restrict__ y2b, float* __restrict__ s2s, float* __restrict__ s2q)
{
    int c = blockIdx.y;
    int m0 = blockIdx.x * 128;
    __shared__ unsigned short Bl[64 * 512];
    __shared__ float red[2][4][64];
    int tid = threadIdx.x;
    int w = tid >> 6, lane = tid & 63;
    int lx = lane & 15, g = lane >> 4;

    const unsigned short* wsrc = w2b + (long)c * 32768;
#pragma unroll
    for (int it = 0; it < 16; ++it) {
        int j = it * 256 + tid;
        int n = j >> 6, kb = j & 63;
        uint4 val = *(const uint4*)(wsrc + n * 512 + kb * 8);
        int dst = (n * 1024 + kb * 16) ^ ((n & 7) << 4);
        *(uint4*)((char*)Bl + dst) = val;
    }
    __syncthreads();

    const unsigned short* abase[2];
#pragma unroll
    for (int ma = 0; ma < 2; ++ma) {
        int m = m0 + w * 32 + ma * 16 + lx;
        m = min(m, 3519);
        int b = m / 55, lp = m % 55;
        abase[ma] = p1b + ((long)(c * 64 + b) * 32) * 124 + 2 * lp + (g & 1) * 8;
    }
    int cio = g >> 1;

    f32x4 acc[2][4] = {};
    for (int kstep = 0; kstep < 16; ++kstep) {
        short8 af[2];
#pragma unroll
        for (int ma = 0; ma < 2; ++ma) {
            const unsigned short* ap = abase[ma] + (kstep * 2 + cio) * 124;
            union { unsigned u[4]; short8 v; } t;
            t.u[0] = *(const unsigned*)(ap + 0);
            t.u[1] = *(const unsigned*)(ap + 2);
            t.u[2] = *(const unsigned*)(ap + 4);
            t.u[3] = *(const unsigned*)(ap + 6);
            af[ma] = t.v;
        }
#pragma unroll
        for (int fi = 0; fi < 4; ++fi) {
            int n = fi * 16 + lx;
            int off = (n * 1024 + kstep * 64 + g * 16) ^ ((n & 7) << 4);
            short8 bfrag = *(const short8*)((char*)Bl + off);
#pragma unroll
            for (int ma = 0; ma < 2; ++ma)
                acc[ma][fi] = __builtin_amdgcn_mfma_f32_16x16x32_bf16(af[ma], bfrag, acc[ma][fi], 0, 0, 0);
        }
    }

    float cs[4] = {}, cq[4] = {};
#pragma unroll
    for (int fi = 0; fi < 4; ++fi) {
        int o2 = fi * 16 + lx;
        float bia = b2[c * 64 + o2];
#pragma unroll
        for (int ma = 0; ma < 2; ++ma) {
#pragma unroll
            for (int r = 0; r < 4; ++r) {
                int mm = m0 + w * 32 + ma * 16 + g * 4 + r;
                if (mm < 3520) {
                    int bb = mm / 55, ll = mm % 55;
                    float y = fmaxf(acc[ma][fi][r] + bia, 0.f);
                    y2b[((long)(c * 64 + bb) * 55 + ll) * 64 + o2] = f2bf(y);
                    cs[fi] += y; cq[fi] += y * y;
                }
            }
        }
    }
#pragma unroll
    for (int fi = 0; fi < 4; ++fi) {
        cs[fi] += __shfl_xor(cs[fi], 16); cs[fi] += __shfl_xor(cs[fi], 32);
        cq[fi] += __shfl_xor(cq[fi], 16); cq[fi] += __shfl_xor(cq[fi], 32);
    }
    __syncthreads();
    if (g == 0) {
#pragma unroll
        for (int fi = 0; fi < 4; ++fi) { red[0][w][fi * 16 + lx] = cs[fi]; red[1][w][fi * 16 + lx] = cq[fi]; }
    }
    __syncthreads();
    if (tid < 64) {
        float ss = red[0][0][tid] + red[0][1][tid] + red[0][2][tid] + red[0][3][tid];
        float qq = red[1][0][tid] + red[1][1][tid] + red[1][2][tid] + red[1][3][tid];
        atomicAdd(&s2s[c * 64 + tid], ss);
        atomicAdd(&s2q[c * 64 + tid], qq);
    }
}

// ---------------- conv2 bn + pool via LDS transpose; block per (c,b) ----------------
__global__ __launch_bounds__(256) void bn2_pool_kernel(const unsigned short* __restrict__ y2b,
    const float* __restrict__ ws, const float* __restrict__ g, const float* __restrict__ be,
    unsigned short* __restrict__ q)
{
    int bid = blockIdx.x;              // c*64+b
    int c = bid >> 6;
    __shared__ unsigned short t2[55][66];
    const unsigned* src = (const unsigned*)(y2b + (long)bid * 3520);
    for (int i = threadIdx.x; i < 1760; i += 256) {
        int r = i >> 5, cu = i & 31;
        *(unsigned*)&t2[r][cu * 2] = src[i];
    }
    __syncthreads();
    float N = (float)(Bn * L2O);
    unsigned short* qp = q + (long)bid * 1728;
    for (int t = threadIdx.x; t < 1728; t += 256) {
        int o2 = t / 27, j = t - o2 * 27;
        int co = c * 64 + o2;
        float m = ws[S2S + co] / N;
        float inv = rsqrtf(ws[S2Q + co] / N - m * m + 1e-5f);
        float sc = inv * g[co], sh = be[co] - m * sc;
        float v = fmaxf(sc * bf2f(t2[2 * j][o2]) + sh, sc * bf2f(t2[2 * j + 1][o2]) + sh);
        qp[t] = f2bf(v);
    }
}

// ---------------- generic MFMA GEMM: C[64,Ntot] = relu(A_bf16[64,K] @ W_fp32[Ntot,K]^T + bias) ----------------
__global__ __launch_bounds__(256) void gemm_a16w32_kernel(const unsigned short* __restrict__ A,
    const float* __restrict__ W, const float* __restrict__ bias, float* __restrict__ C,
    int K, int Ntot, long sA, long sW, long sB, long sC)
{
    int c = blockIdx.y;
    A += (long)c * sA; W += (long)c * sW; bias += (long)c * sB; C += (long)c * sC;
    int n0 = blockIdx.x * 64;
    int tid = threadIdx.x, wv = tid >> 6, lane = tid & 63;
    int lx = lane & 15, g = lane >> 4;
    int wm = wv & 1, wn = wv >> 1;

    const unsigned short* a0 = A + (long)(wm * 32 + lx) * K + g * 8;
    const float* w0 = W + (long)(n0 + wn * 32 + lx) * K + g * 8;
    int ksteps = K >> 5;

    f32x4 acc[2][2] = {};
    for (int kstep = 0; kstep < ksteps; ++kstep) {
        short8 af[2];
        af[0] = *(const short8*)(a0 + kstep * 32);
        af[1] = *(const short8*)(a0 + (long)16 * K + kstep * 32);
        short8 bf[2];
#pragma unroll
        for (int nb = 0; nb < 2; ++nb) {
            const float* wp = w0 + (long)nb * 16 * K + kstep * 32;
            float4 x = *(const float4*)(wp);
            float4 y = *(const float4*)(wp + 4);
            bf[nb] = cvt8(x, y);
        }
#pragma unroll
        for (int ma = 0; ma < 2; ++ma)
#pragma unroll
            for (int nb = 0; nb < 2; ++nb)
                acc[ma][nb] = __builtin_amdgcn_mfma_f32_16x16x32_bf16(af[ma], bf[nb], acc[ma][nb], 0, 0, 0);
    }
#pragma unroll
    for (int ma = 0; ma < 2; ++ma)
#pragma unroll
        for (int nb = 0; nb < 2; ++nb) {
            int o = n0 + wn * 32 + nb * 16 + lx;
            float bia = bias[o];
#pragma unroll
            for (int r = 0; r < 4; ++r) {
                int b = wm * 32 + ma * 16 + g * 4 + r;
                C[(long)b * Ntot + o] = fmaxf(acc[ma][nb][r] + bia, 0.f);
            }
        }
}

// ---------------- fused chebyshev recursion V=64: x0..x4, bf16 stores ----------------
__global__ __launch_bounds__(256) void rec_fused_kernel(const float* __restrict__ Lr,
    const float* __restrict__ co, const int* __restrict__ perm, unsigned short* __restrict__ xkb)
{
    __shared__ float Lt[64 * 64];     // Lt[u][v] = Lr[v][u]
    __shared__ float xA[64][130];
    __shared__ float xB[64][130];
    int tid = threadIdx.x;
    for (int i = tid; i < 4096; i += 256) Lt[(i & 63) * 64 + (i >> 6)] = Lr[i];
    int cg = tid & 31, vg = tid >> 5;
    int col = blockIdx.x * 128 + cg * 4;
#pragma unroll
    for (int i = 0; i < 8; ++i) {
        int v = vg * 8 + i;
        float4 x = *(const float4*)&co[(long)perm[v] * 32768 + col];
        *(float4*)&xA[v][cg * 4] = x;
        *(uint2*)&xkb[(long)v * 32768 + col] = pack4(x);
    }
    __syncthreads();
#pragma unroll
    for (int k = 1; k <= 4; ++k) {
        float (*prev)[130] = (k & 1) ? xA : xB;
        float (*dst)[130]  = (k & 1) ? xB : xA;
        float acc[8][4] = {};
        for (int u = 0; u < 64; ++u) {
            float4 xv = *(const float4*)&prev[u][cg * 4];
            float4 l0 = *(const float4*)&Lt[u * 64 + vg * 8];
            float4 l1 = *(const float4*)&Lt[u * 64 + vg * 8 + 4];
            float lv[8] = {l0.x, l0.y, l0.z, l0.w, l1.x, l1.y, l1.z, l1.w};
#pragma unroll
            for (int i = 0; i < 8; ++i) {
                acc[i][0] = fmaf(lv[i], xv.x, acc[i][0]);
                acc[i][1] = fmaf(lv[i], xv.y, acc[i][1]);
                acc[i][2] = fmaf(lv[i], xv.z, acc[i][2]);
                acc[i][3] = fmaf(lv[i], xv.w, acc[i][3]);
            }
        }
#pragma unroll
        for (int i = 0; i < 8; ++i) {
            int v = vg * 8 + i;
            float4 r;
            if (k == 1) {
                r.x = acc[i][0]; r.y = acc[i][1]; r.z = acc[i][2]; r.w = acc[i][3];
            } else {
                float4 p = *(const float4*)&dst[v][cg * 4];   // holds x_{k-2}
                r.x = 2.f * acc[i][0] - p.x; r.y = 2.f * acc[i][1] - p.y;
                r.z = 2.f * acc[i][2] - p.z; r.w = 2.f * acc[i][3] - p.w;
            }
            *(float4*)&dst[v][cg * 4] = r;
            *(uint2*)&xkb[(long)k * 2097152 + (long)v * 32768 + col] = pack4(r);
        }
        __syncthreads();
    }
}

// ---------------- cheby layer-1 output GEMM, M-tile 16, bf16 A + bf16 weights ----------------
__global__ __launch_bounds__(256) void cheby1_mfma_kernel(const unsigned short* __restrict__ xkb,
    const unsigned short* __restrict__ w1rb, const float* __restrict__ bias, float* __restrict__ out)
{
    int m0 = blockIdx.x * 16;
    __shared__ unsigned short Bl[64 * 512];
    int tid = threadIdx.x, wv = tid >> 6, lane = tid & 63;
    int lx = lane & 15, g = lane >> 4;
    int m = m0 + lx;
    int v = m & 63, b = m >> 6;

    f32x4 acc = {};
    for (int kc = 0; kc < 5; ++kc) {
        __syncthreads();
#pragma unroll
        for (int it = 0; it < 16; ++it) {
            int j = it * 256 + tid;
            int n = j >> 6, kb = j & 63;
            uint4 val = *(const uint4*)(w1rb + (long)kc * 32768 + n * 512 + kb * 8);
            int dst = (n * 1024 + kb * 16) ^ ((n & 7) << 4);
            *(uint4*)((char*)Bl + dst) = val;
        }
        __syncthreads();
        const unsigned short* ab = xkb + (long)(kc * 64 + v) * 32768 + b * 512 + g * 8;
        for (int kl = 0; kl < 16; ++kl) {
            short8 af = *(const short8*)(ab + kl * 32);
            int n = wv * 16 + lx;
            int off = (n * 1024 + kl * 64 + g * 16) ^ ((n & 7) << 4);
            short8 bfrag = *(const short8*)((char*)Bl + off);
            acc = __builtin_amdgcn_mfma_f32_16x16x32_bf16(af, bfrag, acc, 0, 0, 0);
        }
    }
    int o = wv * 16 + lx;
    float bia = bias[o];
#pragma unroll
    for (int r = 0; r < 4; ++r) {
        int mm = m0 + g * 4 + r;
        int vv = mm & 63, bb = mm >> 6;
        out[((long)(bb * 64 + vv)) * 64 + o] = fmaxf(acc[r] + bia, 0.f);
    }
}

// ---------------- graph BN + graph max-pool (fp32 out, cheby layout) ----------------
template<int Fdim, int XOUT>
__global__ __launch_bounds__(256) void gbn_gpool_kernel(const float* __restrict__ y,
    const float* __restrict__ g, const float* __restrict__ be, float eps, int V, float* __restrict__ out)
{
    int j = blockIdx.x; int v0 = 2 * j;
    int tid = threadIdx.x;
    float s0 = 0.f, q0 = 0.f, s1 = 0.f, q1 = 0.f;
    int Ntot = Bn * Fdim;
    for (int idx = tid; idx < Ntot; idx += 256) {
        int b = idx / Fdim, f = idx % Fdim;
        float a = y[((long)b * V + v0) * Fdim + f];
        float c = y[((long)b * V + v0 + 1) * Fdim + f];
        s0 += a; q0 += a * a; s1 += c; q1 += c * c;
    }
    __shared__ float red[4][256];
    red[0][tid] = s0; red[1][tid] = q0; red[2][tid] = s1; red[3][tid] = q1;
    __syncthreads();
    for (int st = 128; st > 0; st >>= 1) {
        if (tid < st) {
#pragma unroll
            for (int r = 0; r < 4; ++r) red[r][tid] += red[r][tid + st];
        }
        __syncthreads();
    }
    float N = (float)Ntot;
    float m0 = red[0][0] / N, i0 = rsqrtf(red[1][0] / N - m0 * m0 + eps);
    float m1 = red[2][0] / N, i1 = rsqrtf(red[3][0] / N - m1 * m1 + eps);
    float sc0 = i0 * g[v0], sh0 = be[v0] - m0 * sc0;
    float sc1 = i1 * g[v0 + 1], sh1 = be[v0 + 1] - m1 * sc1;
    for (int idx = tid; idx < Ntot; idx += 256) {
        int b = idx / Fdim, f = idx % Fdim;
        float a = y[((long)b * V + v0) * Fdim + f];
        float c = y[((long)b * V + v0 + 1) * Fdim + f];
        float r = fmaxf(sc0 * a + sh0, sc1 * c + sh1);
        long oidx = XOUT ? ((long)j * Bn + b) * Fdim + f : ((long)b * (V / 2) + j) * Fdim + f;
        out[oidx] = r;
    }
}

// ---------------- gbn2 + gpool2, bf16 out [b][j*128+f] ----------------
__global__ __launch_bounds__(256) void gbn2_bf16_kernel(const float* __restrict__ y,
    const float* __restrict__ g, const float* __restrict__ be, unsigned short* __restrict__ out)
{
    constexpr int Fdim = 128; constexpr int V = 32;
    int j = blockIdx.x; int v0 = 2 * j;
    int tid = threadIdx.x;
    float s0 = 0.f, q0 = 0.f, s1 = 0.f, q1 = 0.f;
    int Ntot = Bn * Fdim;
    for (int idx = tid; idx < Ntot; idx += 256) {
        int b = idx / Fdim, f = idx % Fdim;
        float a = y[((long)b * V + v0) * Fdim + f];
        float c = y[((long)b * V + v0 + 1) * Fdim + f];
        s0 += a; q0 += a * a; s1 += c; q1 += c * c;
    }
    __shared__ float red[4][256];
    red[0][tid] = s0; red[1][tid] = q0; red[2][tid] = s1; red[3][tid] = q1;
    __syncthreads();
    for (int st = 128; st > 0; st >>= 1) {
        if (tid < st) {
#pragma unroll
            for (int r = 0; r < 4; ++r) red[r][tid] += red[r][tid + st];
        }
        __syncthreads();
    }
    float N = (float)Ntot;
    float m0 = red[0][0] / N, i0 = rsqrtf(red[1][0] / N - m0 * m0 + 128.0f);
    float m1 = red[2][0] / N, i1 = rsqrtf(red[3][0] / N - m1 * m1 + 128.0f);
    float sc0 = i0 * g[v0], sh0 = be[v0] - m0 * sc0;
    float sc1 = i1 * g[v0 + 1], sh1 = be[v0 + 1] - m1 * sc1;
    for (int idx = tid; idx < Ntot; idx += 256) {
        int b = idx / Fdim, f = idx % Fdim;
        float a = y[((long)b * V + v0) * Fdim + f];
        float c = y[((long)b * V + v0 + 1) * Fdim + f];
        float r = fmaxf(sc0 * a + sh0, sc1 * c + sh1);
        out[((long)b * 16 + j) * Fdim + f] = f2bf(r);
    }
}

// ---------------- fused layer 2: cheby recursion (LDS) + MFMA GEMM, one block per b ----------------
__global__ __launch_bounds__(256) void layer2_kernel(const float* __restrict__ x2k0,
    const float* __restrict__ Lr1, const unsigned short* __restrict__ w2rb,
    const float* __restrict__ bias, float* __restrict__ out)
{
    int b = blockIdx.x;
    __shared__ float xs[5][32][72];
    __shared__ unsigned short wsl[128 * 320];
    int tid = threadIdx.x;
#pragma unroll
    for (int it = 0; it < 20; ++it) {
        int j = it * 256 + tid;
        int o = j / 40, kb = j % 40;
        uint4 val = *(const uint4*)(w2rb + ((long)(kb >> 3) * 128 + o) * 64 + (kb & 7) * 8);
        int dst = (o * 640 + kb * 16) ^ ((o & 7) << 4);
        *(uint4*)((char*)wsl + dst) = val;
    }
    int v = tid & 31, fg = tid >> 5;
    float lrow[32];
#pragma unroll
    for (int u = 0; u < 32; ++u) lrow[u] = Lr1[v * 32 + u];
    {
        const float* sp = x2k0 + ((long)v * 64 + b) * 64 + fg * 8;
        float4 a = *(const float4*)sp;
        float4 c = *(const float4*)(sp + 4);
        *(float4*)&xs[0][v][fg * 8] = a;
        *(float4*)&xs[0][v][fg * 8 + 4] = c;
    }
    __syncthreads();
    for (int k = 1; k < 5; ++k) {
        float acc[8] = {};
#pragma unroll
        for (int u = 0; u < 32; ++u) {
            float4 xa = *(const float4*)&xs[k - 1][u][fg * 8];
            float4 xb = *(const float4*)&xs[k - 1][u][fg * 8 + 4];
            float l = lrow[u];
            acc[0] = fmaf(l, xa.x, acc[0]); acc[1] = fmaf(l, xa.y, acc[1]);
            acc[2] = fmaf(l, xa.z, acc[2]); acc[3] = fmaf(l, xa.w, acc[3]);
            acc[4] = fmaf(l, xb.x, acc[4]); acc[5] = fmaf(l, xb.y, acc[5]);
            acc[6] = fmaf(l, xb.z, acc[6]); acc[7] = fmaf(l, xb.w, acc[7]);
        }
        float4 ra, rb;
        if (k >= 2) {
            float4 pa = *(const float4*)&xs[k - 2][v][fg * 8];
            float4 pb = *(const float4*)&xs[k - 2][v][fg * 8 + 4];
            ra.x = 2.f * acc[0] - pa.x; ra.y = 2.f * acc[1] - pa.y;
            ra.z = 2.f * acc[2] - pa.z; ra.w = 2.f * acc[3] - pa.w;
            rb.x = 2.f * acc[4] - pb.x; rb.y = 2.f * acc[5] - pb.y;
            rb.z = 2.f * acc[6] - pb.z; rb.w = 2.f * acc[7] - pb.w;
        } else {
            ra.x = acc[0]; ra.y = acc[1]; ra.z = acc[2]; ra.w = acc[3];
            rb.x = acc[4]; rb.y = acc[5]; rb.z = acc[6]; rb.w = acc[7];
        }
        *(float4*)&xs[k][v][fg * 8] = ra;
        *(float4*)&xs[k][v][fg * 8 + 4] = rb;
        __syncthreads();
    }
    int wv = tid >> 6, lane = tid & 63;
    int lx = lane & 15, g = lane >> 4;
    f32x4 acc2[2][2] = {};
    for (int kstep = 0; kstep < 10; ++kstep) {
        int k = kstep * 32 + g * 8;
        int kc = k >> 6, f = k & 63;
        short8 af[2];
#pragma unroll
        for (int ma = 0; ma < 2; ++ma) {
            int vv = ma * 16 + lx;
            float4 xa = *(const float4*)&xs[kc][vv][f];
            float4 xb = *(const float4*)&xs[kc][vv][f + 4];
            af[ma] = cvt8(xa, xb);
        }
#pragma unroll
        for (int nb = 0; nb < 2; ++nb) {
            int o = wv * 32 + nb * 16 + lx;
            int kb = kstep * 4 + g;
            int off = (o * 640 + kb * 16) ^ ((o & 7) << 4);
            short8 bf = *(const short8*)((char*)wsl + off);
#pragma unroll
            for (int ma = 0; ma < 2; ++ma)
                acc2[ma][nb] = __builtin_amdgcn_mfma_f32_16x16x32_bf16(af[ma], bf, acc2[ma][nb], 0, 0, 0);
        }
    }
#pragma unroll
    for (int ma = 0; ma < 2; ++ma)
#pragma unroll
        for (int nb = 0; nb < 2; ++nb) {
            int o = wv * 32 + nb * 16 + lx;
            float bia = bias[o];
#pragma unroll
            for (int r = 0; r < 4; ++r) {
                int vv = ma * 16 + g * 4 + r;
                out[((long)b * 32 + vv) * 128 + o] = fmaxf(acc2[ma][nb][r] + bia, 0.f);
            }
        }
}

// ---------------- fc2 ----------------
__global__ void fc2_kernel(const float* __restrict__ x, const float* __restrict__ w,
                           const float* __restrict__ bv, float* __restrict__ out)
{
    int tid = threadIdx.x;   // 128 threads
    int b = tid >> 1, o = tid & 1;
    float acc = bv[o];
    for (int f = 0; f < 512; ++f) acc = fmaf(x[b * 512 + f], w[o * 512 + f], acc);
    out[tid] = acc;
}

// ---------------- launch ----------------
extern "C" void kernel_launch(void* const* d_in, const int* in_sizes, int n_in,
                              void* d_out, int out_size, void* d_ws, size_t ws_size,
                              hipStream_t stream)
{
    const float* inp    = (const float*)d_in[0];
    const float* L0     = (const float*)d_in[2];
    const float* L1m    = (const float*)d_in[3];
    const int*   lmax0  = (const int*)d_in[4];
    const int*   lmax1  = (const int*)d_in[5];
    const int*   perm   = (const int*)d_in[6];
    const float* conv1_w = (const float*)d_in[8];
    const float* conv1_b = (const float*)d_in[9];
    const float* bn1_g  = (const float*)d_in[10];
    const float* bn1_b  = (const float*)d_in[11];
    const float* conv2_w = (const float*)d_in[12];
    const float* conv2_b = (const float*)d_in[13];
    const float* bn2_g  = (const float*)d_in[14];
    const float* bn2_b  = (const float*)d_in[15];
    const float* lin1_w = (const float*)d_in[16];
    const float* lin1_b = (const float*)d_in[17];
    const float* cl1_w  = (const float*)d_in[18];
    const float* cl1_b  = (const float*)d_in[19];
    const float* gbn1_g = (const float*)d_in[20];
    const float* gbn1_b = (const float*)d_in[21];
    const float* cl2_w  = (const float*)d_in[22];
    const float* cl2_b  = (const float*)d_in[23];
    const float* gbn2_g = (const float*)d_in[24];
    const float* gbn2_b = (const float*)d_in[25];
    const float* fc1_w  = (const float*)d_in[26];
    const float* fc1_b  = (const float*)d_in[27];
    const float* fc2_w  = (const float*)d_in[28];
    const float* fc2_b  = (const float*)d_in[29];
    float* ws  = (float*)d_ws;
    char*  wsb = (char*)d_ws;
    float* out = (float*)d_out;

    unsigned short* w1rb = (unsigned short*)(wsb + W1RB_B);
    unsigned short* w2rb = (unsigned short*)(wsb + W2RB_B);
    unsigned short* w2b  = (unsigned short*)(wsb + W2B_B);
    unsigned short* p1b  = (unsigned short*)(wsb + P1B_B);
    unsigned short* y2b  = (unsigned short*)(wsb + Y2_B);
    unsigned short* qb   = (unsigned short*)(wsb + QB_B);
    float*          co   = (float*)(wsb + CO_B);
    unsigned short* xkb  = (unsigned short*)(wsb + XK_B);
    float*          ch1  = (float*)(wsb + CH1_B);
    float*          x2k0 = (float*)(wsb + X2K_B);
    float*          ch2  = (float*)(wsb + CH2_B);
    unsigned short* fci  = (unsigned short*)(wsb + FCI_B);
    float*          fo1  = (float*)(wsb + FO1_B);
    float*          lr0  = (float*)(wsb + LR0_B);
    float*          lr1  = (float*)(wsb + LR1_B);

    // 0. prep (zeros all stat accumulators + Lr + repacks)
    prep_kernel<<<9060, 256, 0, stream>>>(L0, L1m, lmax0, lmax1, cl1_w, cl2_w, conv2_w, ws);

    // 1. conv1: stats pass + bn/pool pass -> p1b bf16
    conv1_p1_kernel<<<512, 256, 0, stream>>>(inp, conv1_w, conv1_b, ws);
    conv1_p2_kernel<<<512, 256, 0, stream>>>(inp, conv1_w, conv1_b, bn1_g, bn1_b, ws, p1b);

    // 2. conv2 MFMA (M-tile 128) -> y2 bf16; bn+pool (LDS transpose) -> qb bf16
    conv2_mfma_kernel<<<dim3(28, 64), 256, 0, stream>>>(p1b, w2b, conv2_b, y2b, ws + S2S, ws + S2Q);
    bn2_pool_kernel<<<4096, 256, 0, stream>>>(y2b, ws, bn2_g, bn2_b, qb);

    // 3. lin1 MFMA -> co fp32
    gemm_a16w32_kernel<<<dim3(8, 64), 256, 0, stream>>>(qb, lin1_w, lin1_b, co,
        LIN1K, 512, (long)64 * LIN1K, (long)512 * LIN1K, 512, (long)64 * 512);

    // 4. cheby layer 1: fused recursion (bf16 xk stores) then MFMA output GEMM (bf16 A)
    rec_fused_kernel<<<256, 256, 0, stream>>>(lr0, co, perm, xkb);
    cheby1_mfma_kernel<<<256, 256, 0, stream>>>(xkb, w1rb, cl1_b, ch1);

    // 5. gbn1 + gpool1 -> x2k0 [v'][b][f]
    gbn_gpool_kernel<64, 1><<<32, 256, 0, stream>>>(ch1, gbn1_g, gbn1_b, 64.0f, 64, x2k0);

    // 6. fused layer 2 (recursion + cheby GEMM) -> ch2 [b][v][o]
    layer2_kernel<<<64, 256, 0, stream>>>(x2k0, lr1, w2rb, cl2_b, ch2);

    // 7. gbn2 + gpool2 -> fci bf16 [b][2048]
    gbn2_bf16_kernel<<<16, 256, 0, stream>>>(ch2, gbn2_g, gbn2_b, fci);

    // 8. fc1 MFMA + fc2
    gemm_a16w32_kernel<<<dim3(8, 1), 256, 0, stream>>>(fci, fc1_w, fc1_b, fo1,
        2048, 512, 0, 0, 0, 0);
    fc2_kernel<<<1, 128, 0, stream>>>(fo1, fc2_w, fc2_b, out);
}

// Round 10
// 345.009 us; speedup vs baseline: 1.0565x; 1.0072x over previous
//
#include <hip/hip_runtime.h>
#include <hip/hip_bf16.h>

typedef __attribute__((ext_vector_type(8))) short short8;
typedef __attribute__((ext_vector_type(4))) float f32x4;

// ---------------- constants ----------------
namespace {
constexpr int Bn  = 64;
constexpr int Cn  = 64;
constexpr int C1O = 32, C2O = 64;
constexpr int L1O = 249, L1P = 124;
constexpr int L2O = 55,  L2P = 27;
constexpr int FIN1 = 512;
constexpr int LIN1K = C2O * L2P;      // 1728

// stats floats
constexpr long S1S = 0;          // 2048 conv1 sum
constexpr long S1Q = 2048;       // 2048 conv1 sumsq
constexpr long S2S = 4096;       // 4096 conv2 sum
constexpr long S2Q = 8192;       // 4096 conv2 sumsq   (all zeroed by prep)

// byte offsets
constexpr long LR0_B  = 65536;       // 4096 f
constexpr long LR1_B  = 81920;       // 1024 f
constexpr long W1RB_B = 86016;       // 163840 bf16
constexpr long W2RB_B = 413696;      // 40960 bf16
constexpr long W2B_B  = 495616;      // 2097152 bf16 -> 4689920
constexpr long P1B_B  = 4689920;     // 16252928 bf16 -> 37195776
constexpr long Y2_B   = 37195776;    // 14417920 bf16 -> 66031616
constexpr long QB_B   = 94867456;    // 7077888 bf16
constexpr long CO_B   = 109023232;   // 2097152 f
constexpr long XK_B   = 4689920;     // alias p1b/y2 (dead): 5*2097152 bf16 -> 25661440
constexpr long CH1_B  = 117411840;   // 262144 f
constexpr long X2K_B  = 118460416;   // 131072 f
constexpr long CH2_B  = 118984704;   // 262144 f
constexpr long FCI_B  = 120033280;   // 131072 bf16
constexpr long FO1_B  = 120295424;   // 32768 f
}

__device__ __forceinline__ unsigned short f2bf(float f) {
    union { float f; unsigned u; } v; v.f = f;
    unsigned r = v.u + 0x7FFFu + ((v.u >> 16) & 1u);
    return (unsigned short)(r >> 16);
}
__device__ __forceinline__ float bf2f(unsigned short s) {
    union { unsigned u; float f; } v; v.u = ((unsigned)s) << 16;
    return v.f;
}
__device__ __forceinline__ short8 cvt8(float4 a, float4 b) {
    float f[8] = {a.x, a.y, a.z, a.w, b.x, b.y, b.z, b.w};
    union { unsigned short s[8]; short8 v; } r;
#pragma unroll
    for (int i = 0; i < 8; ++i) r.s[i] = f2bf(f[i]);
    return r.v;
}
__device__ __forceinline__ uint2 pack4(float4 a) {
    union { unsigned short s[4]; uint2 u; } r;
    r.s[0] = f2bf(a.x); r.s[1] = f2bf(a.y); r.s[2] = f2bf(a.z); r.s[3] = f2bf(a.w);
    return r.u;
}

// ---------------- prep: zero stats + Lr + cheby bf16 repacks + conv2_w bf16 ----------------
__global__ void prep_kernel(const float* __restrict__ L0, const float* __restrict__ L1m,
                            const int* __restrict__ lmax0, const int* __restrict__ lmax1,
                            const float* __restrict__ cl1w, const float* __restrict__ cl2w,
                            const float* __restrict__ conv2w, float* __restrict__ ws)
{
    long idx = (long)blockIdx.x * 256 + threadIdx.x;
    float inv0 = 2.0f / (float)lmax0[0];
    float inv1 = 2.0f / (float)lmax1[0];
    char* wsb = (char*)ws;
    float* LR0p = (float*)(wsb + LR0_B);
    float* LR1p = (float*)(wsb + LR1_B);
    unsigned short* W1Rp = (unsigned short*)(wsb + W1RB_B);
    unsigned short* W2Rp = (unsigned short*)(wsb + W2RB_B);
    unsigned short* w2b  = (unsigned short*)(wsb + W2B_B);
    if (idx < 12288) {
        ws[idx] = 0.f;
    } else if (idx < 12288 + 4096) {
        long t = idx - 12288; int i = t / 64, j = t % 64;
        LR0p[t] = L0[t] * inv0 - (i == j ? 1.0f : 0.0f);
    } else if (idx < 12288 + 4096 + 1024) {
        long t = idx - 12288 - 4096; int i = t / 32, j = t % 32;
        LR1p[t] = L1m[t] * inv1 - (i == j ? 1.0f : 0.0f);
    } else if (idx < 12288 + 4096 + 1024 + 163840) {
        long t = idx - 12288 - 4096 - 1024;
        int k = t / 32768; int r = t % 32768; int o = r / 512, f = r % 512;
        W1Rp[t] = f2bf(cl1w[o * 2560 + f * 5 + k]);
    } else if (idx < 12288 + 4096 + 1024 + 163840 + 40960) {
        long t = idx - 12288 - 4096 - 1024 - 163840;
        int k = t / 8192; int r = t % 8192; int o = r / 64, f = r % 64;
        W2Rp[t] = f2bf(cl2w[o * 320 + f * 5 + k]);
    } else if (idx < 12288 + 4096 + 1024 + 163840 + 40960 + 2097152) {
        long t = idx - 12288 - 4096 - 1024 - 163840 - 40960;
        w2b[t] = f2bf(conv2w[t]);
    }
}

// ---------------- conv1 pass1: conv+relu+stats; block = (c, 8-batch group) ----------------
__global__ __launch_bounds__(256) void conv1_p1_kernel(const float* __restrict__ inp,
    const float* __restrict__ w1, const float* __restrict__ b1, float* __restrict__ ws)
{
    int c = blockIdx.x >> 3, bg = blockIdx.x & 7;
    __shared__ float xs[8][512];
    __shared__ float rs[8][32], rq[8][32];
    int tid = threadIdx.x;
#pragma unroll
    for (int it = 0; it < 4; ++it) {
        int f4 = it * 256 + tid;
        int bl = f4 >> 7, off = (f4 & 127) * 4;
        *(float4*)&xs[bl][off] = *(const float4*)&inp[((long)(bg * 8 + bl) * 64 + c) * 512 + off];
    }
    int o = tid & 31, bq = tid >> 5;
    int co = c * 32 + o;
    float w[16];
#pragma unroll
    for (int t = 0; t < 16; ++t) w[t] = w1[co * 16 + t];
    float bias = b1[co];
    __syncthreads();
    float s = 0.f, q = 0.f;
    for (int jg = 0; jg < 31; ++jg) {
        float x[32];
#pragma unroll
        for (int h = 0; h < 8; ++h) *(float4*)&x[h * 4] = *(const float4*)&xs[bq][jg * 16 + h * 4];
#pragma unroll
        for (int j = 0; j < 8; ++j) {
            float a = bias;
#pragma unroll
            for (int t = 0; t < 16; ++t) a = fmaf(x[2 * j + t], w[t], a);
            a = fmaxf(a, 0.f);
            s += a; q += a * a;
        }
    }
    {   // l = 248
        float x[16];
#pragma unroll
        for (int h = 0; h < 4; ++h) *(float4*)&x[h * 4] = *(const float4*)&xs[bq][496 + h * 4];
        float a = bias;
#pragma unroll
        for (int t = 0; t < 16; ++t) a = fmaf(x[t], w[t], a);
        a = fmaxf(a, 0.f);
        s += a; q += a * a;
    }
    rs[bq][o] = s; rq[bq][o] = q;
    __syncthreads();
    if (tid < 32) {
        float ss = 0.f, qq = 0.f;
#pragma unroll
        for (int i = 0; i < 8; ++i) { ss += rs[i][tid]; qq += rq[i][tid]; }
        atomicAdd(&ws[S1S + c * 32 + tid], ss);
        atomicAdd(&ws[S1Q + c * 32 + tid], qq);
    }
}

// ---------------- conv1 pass2: conv+bn+pool -> p1b bf16 [c][b][o][124] ----------------
__global__ __launch_bounds__(256) void conv1_p2_kernel(const float* __restrict__ inp,
    const float* __restrict__ w1, const float* __restrict__ b1,
    const float* __restrict__ g, const float* __restrict__ be,
    const float* __restrict__ ws, unsigned short* __restrict__ p1)
{
    int c = blockIdx.x >> 3, bg = blockIdx.x & 7;
    __shared__ float xs[8][512];
    int tid = threadIdx.x;
#pragma unroll
    for (int it = 0; it < 4; ++it) {
        int f4 = it * 256 + tid;
        int bl = f4 >> 7, off = (f4 & 127) * 4;
        *(float4*)&xs[bl][off] = *(const float4*)&inp[((long)(bg * 8 + bl) * 64 + c) * 512 + off];
    }
    int o = tid & 31, bq = tid >> 5;
    int co = c * 32 + o;
    float w[16];
#pragma unroll
    for (int t = 0; t < 16; ++t) w[t] = w1[co * 16 + t];
    float bias = b1[co];
    float N = (float)(Bn * L1O);
    float m = ws[S1S + co] / N;
    float inv = rsqrtf(ws[S1Q + co] / N - m * m + 1e-5f);
    float sc = inv * g[co], sh = be[co] - m * sc;
    __syncthreads();
    unsigned short* op = p1 + ((long)(c * 64 + bg * 8 + bq) * 32 + o) * 124;
    for (int jg = 0; jg < 31; ++jg) {
        float x[32];
#pragma unroll
        for (int h = 0; h < 8; ++h) *(float4*)&x[h * 4] = *(const float4*)&xs[bq][jg * 16 + h * 4];
        union { unsigned short r[4]; uint2 u; } pk;
#pragma unroll
        for (int p = 0; p < 4; ++p) {
            float a0 = bias, a1 = bias;
#pragma unroll
            for (int t = 0; t < 16; ++t) {
                a0 = fmaf(x[4 * p + t], w[t], a0);
                a1 = fmaf(x[4 * p + 2 + t], w[t], a1);
            }
            float v0 = fmaxf(a0, 0.f) * sc + sh;
            float v1 = fmaxf(a1, 0.f) * sc + sh;
            pk.r[p] = f2bf(fmaxf(v0, v1));
        }
        *(uint2*)&op[jg * 4] = pk.u;
    }
}

// ---------------- conv2 MFMA GEMM, M-tile 128 + relu + stats; y2 bf16 [c][b][l][o2] ----------------
__global__ __launch_bounds__(256) void conv2_mfma_kernel(const unsigned short* __restrict__ p1b,
    const unsigned short* __restrict__ w2b, const float* __restrict__ b2,
    unsigned short* __restrict__ y2b, float* __restrict__ s2s, float* __restrict__ s2q)
{
    int c = blockIdx.y;
    int m0 = blockIdx.x * 128;
    __shared__ unsigned short Bl[64 * 512];
    __shared__ float red[2][4][64];
    int tid = threadIdx.x;
    int w = tid >> 6, lane = tid & 63;
    int lx = lane & 15, g = lane >> 4;

    const unsigned short* wsrc = w2b + (long)c * 32768;
#pragma unroll
    for (int it = 0; it < 16; ++it) {
        int j = it * 256 + tid;
        int n = j >> 6, kb = j & 63;
        uint4 val = *(const uint4*)(wsrc + n * 512 + kb * 8);
        int dst = (n * 1024 + kb * 16) ^ ((n & 7) << 4);
        *(uint4*)((char*)Bl + dst) = val;
    }
    __syncthreads();

    const unsigned short* abase[2];
#pragma unroll
    for (int ma = 0; ma < 2; ++ma) {
        int m = m0 + w * 32 + ma * 16 + lx;
        m = min(m, 3519);
        int b = m / 55, lp = m % 55;
        abase[ma] = p1b + ((long)(c * 64 + b) * 32) * 124 + 2 * lp + (g & 1) * 8;
    }
    int cio = g >> 1;

    f32x4 acc[2][4] = {};
    for (int kstep = 0; kstep < 16; ++kstep) {
        short8 af[2];
#pragma unroll
        for (int ma = 0; ma < 2; ++ma) {
            const unsigned short* ap = abase[ma] + (kstep * 2 + cio) * 124;
            union { unsigned u[4]; short8 v; } t;
            t.u[0] = *(const unsigned*)(ap + 0);
            t.u[1] = *(const unsigned*)(ap + 2);
            t.u[2] = *(const unsigned*)(ap + 4);
            t.u[3] = *(const unsigned*)(ap + 6);
            af[ma] = t.v;
        }
#pragma unroll
        for (int fi = 0; fi < 4; ++fi) {
            int n = fi * 16 + lx;
            int off = (n * 1024 + kstep * 64 + g * 16) ^ ((n & 7) << 4);
            short8 bfrag = *(const short8*)((char*)Bl + off);
#pragma unroll
            for (int ma = 0; ma < 2; ++ma)
                acc[ma][fi] = __builtin_amdgcn_mfma_f32_16x16x32_bf16(af[ma], bfrag, acc[ma][fi], 0, 0, 0);
        }
    }

    float cs[4] = {}, cq[4] = {};
#pragma unroll
    for (int fi = 0; fi < 4; ++fi) {
        int o2 = fi * 16 + lx;
        float bia = b2[c * 64 + o2];
#pragma unroll
        for (int ma = 0; ma < 2; ++ma) {
#pragma unroll
            for (int r = 0; r < 4; ++r) {
                int mm = m0 + w * 32 + ma * 16 + g * 4 + r;
                if (mm < 3520) {
                    int bb = mm / 55, ll = mm % 55;
                    float y = fmaxf(acc[ma][fi][r] + bia, 0.f);
                    y2b[((long)(c * 64 + bb) * 55 + ll) * 64 + o2] = f2bf(y);
                    cs[fi] += y; cq[fi] += y * y;
                }
            }
        }
    }
#pragma unroll
    for (int fi = 0; fi < 4; ++fi) {
        cs[fi] += __shfl_xor(cs[fi], 16); cs[fi] += __shfl_xor(cs[fi], 32);
        cq[fi] += __shfl_xor(cq[fi], 16); cq[fi] += __shfl_xor(cq[fi], 32);
    }
    __syncthreads();
    if (g == 0) {
#pragma unroll
        for (int fi = 0; fi < 4; ++fi) { red[0][w][fi * 16 + lx] = cs[fi]; red[1][w][fi * 16 + lx] = cq[fi]; }
    }
    __syncthreads();
    if (tid < 64) {
        float ss = red[0][0][tid] + red[0][1][tid] + red[0][2][tid] + red[0][3][tid];
        float qq = red[1][0][tid] + red[1][1][tid] + red[1][2][tid] + red[1][3][tid];
        atomicAdd(&s2s[c * 64 + tid], ss);
        atomicAdd(&s2q[c * 64 + tid], qq);
    }
}

// ---------------- conv2 bn + pool via LDS transpose; block per (c,b) ----------------
__global__ __launch_bounds__(256) void bn2_pool_kernel(const unsigned short* __restrict__ y2b,
    const float* __restrict__ ws, const float* __restrict__ g, const float* __restrict__ be,
    unsigned short* __restrict__ q)
{
    int bid = blockIdx.x;              // c*64+b
    int c = bid >> 6;
    __shared__ unsigned short t2[55][66];
    const unsigned* src = (const unsigned*)(y2b + (long)bid * 3520);
    for (int i = threadIdx.x; i < 1760; i += 256) {
        int r = i >> 5, cu = i & 31;
        *(unsigned*)&t2[r][cu * 2] = src[i];
    }
    __syncthreads();
    float N = (float)(Bn * L2O);
    unsigned short* qp = q + (long)bid * 1728;
    for (int t = threadIdx.x; t < 1728; t += 256) {
        int o2 = t / 27, j = t - o2 * 27;
        int co = c * 64 + o2;
        float m = ws[S2S + co] / N;
        float inv = rsqrtf(ws[S2Q + co] / N - m * m + 1e-5f);
        float sc = inv * g[co], sh = be[co] - m * sc;
        float v = fmaxf(sc * bf2f(t2[2 * j][o2]) + sh, sc * bf2f(t2[2 * j + 1][o2]) + sh);
        qp[t] = f2bf(v);
    }
}

// ---------------- generic MFMA GEMM: C[64,Ntot] = relu(A_bf16[64,K] @ W_fp32[Ntot,K]^T + bias) ----------------
__global__ __launch_bounds__(256) void gemm_a16w32_kernel(const unsigned short* __restrict__ A,
    const float* __restrict__ W, const float* __restrict__ bias, float* __restrict__ C,
    int K, int Ntot, long sA, long sW, long sB, long sC)
{
    int c = blockIdx.y;
    A += (long)c * sA; W += (long)c * sW; bias += (long)c * sB; C += (long)c * sC;
    int n0 = blockIdx.x * 64;
    int tid = threadIdx.x, wv = tid >> 6, lane = tid & 63;
    int lx = lane & 15, g = lane >> 4;
    int wm = wv & 1, wn = wv >> 1;

    const unsigned short* a0 = A + (long)(wm * 32 + lx) * K + g * 8;
    const float* w0 = W + (long)(n0 + wn * 32 + lx) * K + g * 8;
    int ksteps = K >> 5;

    f32x4 acc[2][2] = {};
    for (int kstep = 0; kstep < ksteps; ++kstep) {
        short8 af[2];
        af[0] = *(const short8*)(a0 + kstep * 32);
        af[1] = *(const short8*)(a0 + (long)16 * K + kstep * 32);
        short8 bf[2];
#pragma unroll
        for (int nb = 0; nb < 2; ++nb) {
            const float* wp = w0 + (long)nb * 16 * K + kstep * 32;
            float4 x = *(const float4*)(wp);
            float4 y = *(const float4*)(wp + 4);
            bf[nb] = cvt8(x, y);
        }
#pragma unroll
        for (int ma = 0; ma < 2; ++ma)
#pragma unroll
            for (int nb = 0; nb < 2; ++nb)
                acc[ma][nb] = __builtin_amdgcn_mfma_f32_16x16x32_bf16(af[ma], bf[nb], acc[ma][nb], 0, 0, 0);
    }
#pragma unroll
    for (int ma = 0; ma < 2; ++ma)
#pragma unroll
        for (int nb = 0; nb < 2; ++nb) {
            int o = n0 + wn * 32 + nb * 16 + lx;
            float bia = bias[o];
#pragma unroll
            for (int r = 0; r < 4; ++r) {
                int b = wm * 32 + ma * 16 + g * 4 + r;
                C[(long)b * Ntot + o] = fmaxf(acc[ma][nb][r] + bia, 0.f);
            }
        }
}

// ---------------- fused chebyshev recursion V=64: x0..x4, bf16 stores ----------------
__global__ __launch_bounds__(256) void rec_fused_kernel(const float* __restrict__ Lr,
    const float* __restrict__ co, const int* __restrict__ perm, unsigned short* __restrict__ xkb)
{
    __shared__ float Lt[64 * 64];     // Lt[u][v] = Lr[v][u]
    __shared__ float xA[64][130];
    __shared__ float xB[64][130];
    int tid = threadIdx.x;
    for (int i = tid; i < 4096; i += 256) Lt[(i & 63) * 64 + (i >> 6)] = Lr[i];
    int cg = tid & 31, vg = tid >> 5;
    int col = blockIdx.x * 128 + cg * 4;
#pragma unroll
    for (int i = 0; i < 8; ++i) {
        int v = vg * 8 + i;
        float4 x = *(const float4*)&co[(long)perm[v] * 32768 + col];
        *(float4*)&xA[v][cg * 4] = x;
        *(uint2*)&xkb[(long)v * 32768 + col] = pack4(x);
    }
    __syncthreads();
#pragma unroll
    for (int k = 1; k <= 4; ++k) {
        float (*prev)[130] = (k & 1) ? xA : xB;
        float (*dst)[130]  = (k & 1) ? xB : xA;
        float acc[8][4] = {};
        for (int u = 0; u < 64; ++u) {
            float4 xv = *(const float4*)&prev[u][cg * 4];
            float4 l0 = *(const float4*)&Lt[u * 64 + vg * 8];
            float4 l1 = *(const float4*)&Lt[u * 64 + vg * 8 + 4];
            float lv[8] = {l0.x, l0.y, l0.z, l0.w, l1.x, l1.y, l1.z, l1.w};
#pragma unroll
            for (int i = 0; i < 8; ++i) {
                acc[i][0] = fmaf(lv[i], xv.x, acc[i][0]);
                acc[i][1] = fmaf(lv[i], xv.y, acc[i][1]);
                acc[i][2] = fmaf(lv[i], xv.z, acc[i][2]);
                acc[i][3] = fmaf(lv[i], xv.w, acc[i][3]);
            }
        }
#pragma unroll
        for (int i = 0; i < 8; ++i) {
            int v = vg * 8 + i;
            float4 r;
            if (k == 1) {
                r.x = acc[i][0]; r.y = acc[i][1]; r.z = acc[i][2]; r.w = acc[i][3];
            } else {
                float4 p = *(const float4*)&dst[v][cg * 4];   // holds x_{k-2}
                r.x = 2.f * acc[i][0] - p.x; r.y = 2.f * acc[i][1] - p.y;
                r.z = 2.f * acc[i][2] - p.z; r.w = 2.f * acc[i][3] - p.w;
            }
            *(float4*)&dst[v][cg * 4] = r;
            *(uint2*)&xkb[(long)k * 2097152 + (long)v * 32768 + col] = pack4(r);
        }
        __syncthreads();
    }
}

// ---------------- cheby layer-1 output GEMM, M-tile 16, bf16 A + bf16 weights ----------------
__global__ __launch_bounds__(256) void cheby1_mfma_kernel(const unsigned short* __restrict__ xkb,
    const unsigned short* __restrict__ w1rb, const float* __restrict__ bias, float* __restrict__ out)
{
    int m0 = blockIdx.x * 16;
    __shared__ unsigned short Bl[64 * 512];
    int tid = threadIdx.x, wv = tid >> 6, lane = tid & 63;
    int lx = lane & 15, g = lane >> 4;
    int m = m0 + lx;
    int v = m & 63, b = m >> 6;

    f32x4 acc = {};
    for (int kc = 0; kc < 5; ++kc) {
        __syncthreads();
#pragma unroll
        for (int it = 0; it < 16; ++it) {
            int j = it * 256 + tid;
            int n = j >> 6, kb = j & 63;
            uint4 val = *(const uint4*)(w1rb + (long)kc * 32768 + n * 512 + kb * 8);
            int dst = (n * 1024 + kb * 16) ^ ((n & 7) << 4);
            *(uint4*)((char*)Bl + dst) = val;
        }
        __syncthreads();
        const unsigned short* ab = xkb + (long)(kc * 64 + v) * 32768 + b * 512 + g * 8;
        for (int kl = 0; kl < 16; ++kl) {
            short8 af = *(const short8*)(ab + kl * 32);
            int n = wv * 16 + lx;
            int off = (n * 1024 + kl * 64 + g * 16) ^ ((n & 7) << 4);
            short8 bfrag = *(const short8*)((char*)Bl + off);
            acc = __builtin_amdgcn_mfma_f32_16x16x32_bf16(af, bfrag, acc, 0, 0, 0);
        }
    }
    int o = wv * 16 + lx;
    float bia = bias[o];
#pragma unroll
    for (int r = 0; r < 4; ++r) {
        int mm = m0 + g * 4 + r;
        int vv = mm & 63, bb = mm >> 6;
        out[((long)(bb * 64 + vv)) * 64 + o] = fmaxf(acc[r] + bia, 0.f);
    }
}

// ---------------- graph BN + graph max-pool (fp32 out, cheby layout) ----------------
template<int Fdim, int XOUT>
__global__ __launch_bounds__(256) void gbn_gpool_kernel(const float* __restrict__ y,
    const float* __restrict__ g, const float* __restrict__ be, float eps, int V, float* __restrict__ out)
{
    int j = blockIdx.x; int v0 = 2 * j;
    int tid = threadIdx.x;
    float s0 = 0.f, q0 = 0.f, s1 = 0.f, q1 = 0.f;
    int Ntot = Bn * Fdim;
    for (int idx = tid; idx < Ntot; idx += 256) {
        int b = idx / Fdim, f = idx % Fdim;
        float a = y[((long)b * V + v0) * Fdim + f];
        float c = y[((long)b * V + v0 + 1) * Fdim + f];
        s0 += a; q0 += a * a; s1 += c; q1 += c * c;
    }
    __shared__ float red[4][256];
    red[0][tid] = s0; red[1][tid] = q0; red[2][tid] = s1; red[3][tid] = q1;
    __syncthreads();
    for (int st = 128; st > 0; st >>= 1) {
        if (tid < st) {
#pragma unroll
            for (int r = 0; r < 4; ++r) red[r][tid] += red[r][tid + st];
        }
        __syncthreads();
    }
    float N = (float)Ntot;
    float m0 = red[0][0] / N, i0 = rsqrtf(red[1][0] / N - m0 * m0 + eps);
    float m1 = red[2][0] / N, i1 = rsqrtf(red[3][0] / N - m1 * m1 + eps);
    float sc0 = i0 * g[v0], sh0 = be[v0] - m0 * sc0;
    float sc1 = i1 * g[v0 + 1], sh1 = be[v0 + 1] - m1 * sc1;
    for (int idx = tid; idx < Ntot; idx += 256) {
        int b = idx / Fdim, f = idx % Fdim;
        float a = y[((long)b * V + v0) * Fdim + f];
        float c = y[((long)b * V + v0 + 1) * Fdim + f];
        float r = fmaxf(sc0 * a + sh0, sc1 * c + sh1);
        long oidx = XOUT ? ((long)j * Bn + b) * Fdim + f : ((long)b * (V / 2) + j) * Fdim + f;
        out[oidx] = r;
    }
}

// ---------------- gbn2 + gpool2, bf16 out [b][j*128+f] ----------------
__global__ __launch_bounds__(256) void gbn2_bf16_kernel(const float* __restrict__ y,
    const float* __restrict__ g, const float* __restrict__ be, unsigned short* __restrict__ out)
{
    constexpr int Fdim = 128; constexpr int V = 32;
    int j = blockIdx.x; int v0 = 2 * j;
    int tid = threadIdx.x;
    float s0 = 0.f, q0 = 0.f, s1 = 0.f, q1 = 0.f;
    int Ntot = Bn * Fdim;
    for (int idx = tid; idx < Ntot; idx += 256) {
        int b = idx / Fdim, f = idx % Fdim;
        float a = y[((long)b * V + v0) * Fdim + f];
        float c = y[((long)b * V + v0 + 1) * Fdim + f];
        s0 += a; q0 += a * a; s1 += c; q1 += c * c;
    }
    __shared__ float red[4][256];
    red[0][tid] = s0; red[1][tid] = q0; red[2][tid] = s1; red[3][tid] = q1;
    __syncthreads();
    for (int st = 128; st > 0; st >>= 1) {
        if (tid < st) {
#pragma unroll
            for (int r = 0; r < 4; ++r) red[r][tid] += red[r][tid + st];
        }
        __syncthreads();
    }
    float N = (float)Ntot;
    float m0 = red[0][0] / N, i0 = rsqrtf(red[1][0] / N - m0 * m0 + 128.0f);
    float m1 = red[2][0] / N, i1 = rsqrtf(red[3][0] / N - m1 * m1 + 128.0f);
    float sc0 = i0 * g[v0], sh0 = be[v0] - m0 * sc0;
    float sc1 = i1 * g[v0 + 1], sh1 = be[v0 + 1] - m1 * sc1;
    for (int idx = tid; idx < Ntot; idx += 256) {
        int b = idx / Fdim, f = idx % Fdim;
        float a = y[((long)b * V + v0) * Fdim + f];
        float c = y[((long)b * V + v0 + 1) * Fdim + f];
        float r = fmaxf(sc0 * a + sh0, sc1 * c + sh1);
        out[((long)b * 16 + j) * Fdim + f] = f2bf(r);
    }
}

// ---------------- fused layer 2: cheby recursion (LDS) + MFMA GEMM, one block per b ----------------
__global__ __launch_bounds__(256) void layer2_kernel(const float* __restrict__ x2k0,
    const float* __restrict__ Lr1, const unsigned short* __restrict__ w2rb,
    const float* __restrict__ bias, float* __restrict__ out)
{
    int b = blockIdx.x;
    __shared__ float xs[5][32][72];
    __shared__ unsigned short wsl[128 * 320];
    int tid = threadIdx.x;
#pragma unroll
    for (int it = 0; it < 20; ++it) {
        int j = it * 256 + tid;
        int o = j / 40, kb = j % 40;
        uint4 val = *(const uint4*)(w2rb + ((long)(kb >> 3) * 128 + o) * 64 + (kb & 7) * 8);
        int dst = (o * 640 + kb * 16) ^ ((o & 7) << 4);
        *(uint4*)((char*)wsl + dst) = val;
    }
    int v = tid & 31, fg = tid >> 5;
    float lrow[32];
#pragma unroll
    for (int u = 0; u < 32; ++u) lrow[u] = Lr1[v * 32 + u];
    {
        const float* sp = x2k0 + ((long)v * 64 + b) * 64 + fg * 8;
        float4 a = *(const float4*)sp;
        float4 c = *(const float4*)(sp + 4);
        *(float4*)&xs[0][v][fg * 8] = a;
        *(float4*)&xs[0][v][fg * 8 + 4] = c;
    }
    __syncthreads();
    for (int k = 1; k < 5; ++k) {
        float acc[8] = {};
#pragma unroll
        for (int u = 0; u < 32; ++u) {
            float4 xa = *(const float4*)&xs[k - 1][u][fg * 8];
            float4 xb = *(const float4*)&xs[k - 1][u][fg * 8 + 4];
            float l = lrow[u];
            acc[0] = fmaf(l, xa.x, acc[0]); acc[1] = fmaf(l, xa.y, acc[1]);
            acc[2] = fmaf(l, xa.z, acc[2]); acc[3] = fmaf(l, xa.w, acc[3]);
            acc[4] = fmaf(l, xb.x, acc[4]); acc[5] = fmaf(l, xb.y, acc[5]);
            acc[6] = fmaf(l, xb.z, acc[6]); acc[7] = fmaf(l, xb.w, acc[7]);
        }
        float4 ra, rb;
        if (k >= 2) {
            float4 pa = *(const float4*)&xs[k - 2][v][fg * 8];
            float4 pb = *(const float4*)&xs[k - 2][v][fg * 8 + 4];
            ra.x = 2.f * acc[0] - pa.x; ra.y = 2.f * acc[1] - pa.y;
            ra.z = 2.f * acc[2] - pa.z; ra.w = 2.f * acc[3] - pa.w;
            rb.x = 2.f * acc[4] - pb.x; rb.y = 2.f * acc[5] - pb.y;
            rb.z = 2.f * acc[6] - pb.z; rb.w = 2.f * acc[7] - pb.w;
        } else {
            ra.x = acc[0]; ra.y = acc[1]; ra.z = acc[2]; ra.w = acc[3];
            rb.x = acc[4]; rb.y = acc[5]; rb.z = acc[6]; rb.w = acc[7];
        }
        *(float4*)&xs[k][v][fg * 8] = ra;
        *(float4*)&xs[k][v][fg * 8 + 4] = rb;
        __syncthreads();
    }
    int wv = tid >> 6, lane = tid & 63;
    int lx = lane & 15, g = lane >> 4;
    f32x4 acc2[2][2] = {};
    for (int kstep = 0; kstep < 10; ++kstep) {
        int k = kstep * 32 + g * 8;
        int kc = k >> 6, f = k & 63;
        short8 af[2];
#pragma unroll
        for (int ma = 0; ma < 2; ++ma) {
            int vv = ma * 16 + lx;
            float4 xa = *(const float4*)&xs[kc][vv][f];
            float4 xb = *(const float4*)&xs[kc][vv][f + 4];
            af[ma] = cvt8(xa, xb);
        }
#pragma unroll
        for (int nb = 0; nb < 2; ++nb) {
            int o = wv * 32 + nb * 16 + lx;
            int kb = kstep * 4 + g;
            int off = (o * 640 + kb * 16) ^ ((o & 7) << 4);
            short8 bf = *(const short8*)((char*)wsl + off);
#pragma unroll
            for (int ma = 0; ma < 2; ++ma)
                acc2[ma][nb] = __builtin_amdgcn_mfma_f32_16x16x32_bf16(af[ma], bf, acc2[ma][nb], 0, 0, 0);
        }
    }
#pragma unroll
    for (int ma = 0; ma < 2; ++ma)
#pragma unroll
        for (int nb = 0; nb < 2; ++nb) {
            int o = wv * 32 + nb * 16 + lx;
            float bia = bias[o];
#pragma unroll
            for (int r = 0; r < 4; ++r) {
                int vv = ma * 16 + g * 4 + r;
                out[((long)b * 32 + vv) * 128 + o] = fmaxf(acc2[ma][nb][r] + bia, 0.f);
            }
        }
}

// ---------------- fc2 ----------------
__global__ void fc2_kernel(const float* __restrict__ x, const float* __restrict__ w,
                           const float* __restrict__ bv, float* __restrict__ out)
{
    int tid = threadIdx.x;   // 128 threads
    int b = tid >> 1, o = tid & 1;
    float acc = bv[o];
    for (int f = 0; f < 512; ++f) acc = fmaf(x[b * 512 + f], w[o * 512 + f], acc);
    out[tid] = acc;
}

// ---------------- launch ----------------
extern "C" void kernel_launch(void* const* d_in, const int* in_sizes, int n_in,
                              void* d_out, int out_size, void* d_ws, size_t ws_size,
                              hipStream_t stream)
{
    const float* inp    = (const float*)d_in[0];
    const float* L0     = (const float*)d_in[2];
    const float* L1m    = (const float*)d_in[3];
    const int*   lmax0  = (const int*)d_in[4];
    const int*   lmax1  = (const int*)d_in[5];
    const int*   perm   = (const int*)d_in[6];
    const float* conv1_w = (const float*)d_in[8];
    const float* conv1_b = (const float*)d_in[9];
    const float* bn1_g  = (const float*)d_in[10];
    const float* bn1_b  = (const float*)d_in[11];
    const float* conv2_w = (const float*)d_in[12];
    const float* conv2_b = (const float*)d_in[13];
    const float* bn2_g  = (const float*)d_in[14];
    const float* bn2_b  = (const float*)d_in[15];
    const float* lin1_w = (const float*)d_in[16];
    const float* lin1_b = (const float*)d_in[17];
    const float* cl1_w  = (const float*)d_in[18];
    const float* cl1_b  = (const float*)d_in[19];
    const float* gbn1_g = (const float*)d_in[20];
    const float* gbn1_b = (const float*)d_in[21];
    const float* cl2_w  = (const float*)d_in[22];
    const float* cl2_b  = (const float*)d_in[23];
    const float* gbn2_g = (const float*)d_in[24];
    const float* gbn2_b = (const float*)d_in[25];
    const float* fc1_w  = (const float*)d_in[26];
    const float* fc1_b  = (const float*)d_in[27];
    const float* fc2_w  = (const float*)d_in[28];
    const float* fc2_b  = (const float*)d_in[29];
    float* ws  = (float*)d_ws;
    char*  wsb = (char*)d_ws;
    float* out = (float*)d_out;

    unsigned short* w1rb = (unsigned short*)(wsb + W1RB_B);
    unsigned short* w2rb = (unsigned short*)(wsb + W2RB_B);
    unsigned short* w2b  = (unsigned short*)(wsb + W2B_B);
    unsigned short* p1b  = (unsigned short*)(wsb + P1B_B);
    unsigned short* y2b  = (unsigned short*)(wsb + Y2_B);
    unsigned short* qb   = (unsigned short*)(wsb + QB_B);
    float*          co   = (float*)(wsb + CO_B);
    unsigned short* xkb  = (unsigned short*)(wsb + XK_B);
    float*          ch1  = (float*)(wsb + CH1_B);
    float*          x2k0 = (float*)(wsb + X2K_B);
    float*          ch2  = (float*)(wsb + CH2_B);
    unsigned short* fci  = (unsigned short*)(wsb + FCI_B);
    float*          fo1  = (float*)(wsb + FO1_B);
    float*          lr0  = (float*)(wsb + LR0_B);
    float*          lr1  = (float*)(wsb + LR1_B);

    // 0. prep (zeros all stat accumulators + Lr + repacks)
    prep_kernel<<<9060, 256, 0, stream>>>(L0, L1m, lmax0, lmax1, cl1_w, cl2_w, conv2_w, ws);

    // 1. conv1: stats pass + bn/pool pass -> p1b bf16
    conv1_p1_kernel<<<512, 256, 0, stream>>>(inp, conv1_w, conv1_b, ws);
    conv1_p2_kernel<<<512, 256, 0, stream>>>(inp, conv1_w, conv1_b, bn1_g, bn1_b, ws, p1b);

    // 2. conv2 MFMA (M-tile 128) -> y2 bf16; bn+pool (LDS transpose) -> qb bf16
    conv2_mfma_kernel<<<dim3(28, 64), 256, 0, stream>>>(p1b, w2b, conv2_b, y2b, ws + S2S, ws + S2Q);
    bn2_pool_kernel<<<4096, 256, 0, stream>>>(y2b, ws, bn2_g, bn2_b, qb);

    // 3. lin1 MFMA -> co fp32
    gemm_a16w32_kernel<<<dim3(8, 64), 256, 0, stream>>>(qb, lin1_w, lin1_b, co,
        LIN1K, 512, (long)64 * LIN1K, (long)512 * LIN1K, 512, (long)64 * 512);

    // 4. cheby layer 1: fused recursion (bf16 xk stores) then MFMA output GEMM (bf16 A)
    rec_fused_kernel<<<256, 256, 0, stream>>>(lr0, co, perm, xkb);
    cheby1_mfma_kernel<<<256, 256, 0, stream>>>(xkb, w1rb, cl1_b, ch1);

    // 5. gbn1 + gpool1 -> x2k0 [v'][b][f]
    gbn_gpool_kernel<64, 1><<<32, 256, 0, stream>>>(ch1, gbn1_g, gbn1_b, 64.0f, 64, x2k0);

    // 6. fused layer 2 (recursion + cheby GEMM) -> ch2 [b][v][o]
    layer2_kernel<<<64, 256, 0, stream>>>(x2k0, lr1, w2rb, cl2_b, ch2);

    // 7. gbn2 + gpool2 -> fci bf16 [b][2048]
    gbn2_bf16_kernel<<<16, 256, 0, stream>>>(ch2, gbn2_g, gbn2_b, fci);

    // 8. fc1 MFMA + fc2
    gemm_a16w32_kernel<<<dim3(8, 1), 256, 0, stream>>>(fci, fc1_w, fc1_b, fo1,
        2048, 512, 0, 0, 0, 0);
    fc2_kernel<<<1, 128, 0, stream>>>(fo1, fc2_w, fc2_b, out);
}